// Round 7
// baseline (5990.369 us; speedup 1.0000x reference)
//
#include <hip/hip_runtime.h>

typedef unsigned short u16;
typedef unsigned int u32;

typedef __bf16 bf16x8 __attribute__((ext_vector_type(8)));
typedef float  f32x4  __attribute__((ext_vector_type(4)));
typedef short  s16x4  __attribute__((ext_vector_type(4)));

#define N_EMBD 384
#define TT     291
#define NB     128

__device__ __forceinline__ u16 f2bf(float x) {
    union { float f; u32 u; } v; v.f = x;
    u32 r = v.u + 0x7FFFu + ((v.u >> 16) & 1u);
    return (u16)(r >> 16);
}
__device__ __forceinline__ float bfl(u32 u) { return __uint_as_float(u << 16); }
__device__ __forceinline__ float bfh(u32 u) { return __uint_as_float(u & 0xFFFF0000u); }

__device__ __forceinline__ float gelu_f(float x) {
    float u = 0.7978845608028654f * x * (1.f + 0.044715f * x * x);
    float e = __expf(2.f * u);
    float t = 1.f - 2.f / (e + 1.f);   // tanh(u), safe at +-inf
    return 0.5f * x * (1.f + t);
}

// K=16 bf16 MFMA (PV step): A/B are 4 bf16 (2 VGPRs), C/D 4 f32.
__device__ __forceinline__ f32x4 mfma16(s16x4 a, s16x4 b, f32x4 c) {
#if __has_builtin(__builtin_amdgcn_mfma_f32_16x16x16bf16_1k)
    return __builtin_amdgcn_mfma_f32_16x16x16bf16_1k(a, b, c, 0, 0, 0);
#elif __has_builtin(__builtin_amdgcn_mfma_f32_16x16x16_bf16)
    typedef __bf16 bf16x4v __attribute__((ext_vector_type(4)));
    return __builtin_amdgcn_mfma_f32_16x16x16_bf16(__builtin_bit_cast(bf16x4v, a),
                                                   __builtin_bit_cast(bf16x4v, b), c, 0, 0, 0);
#else
    f32x4 d = c;
    asm("v_mfma_f32_16x16x16_bf16 %0, %1, %2, %0" : "+v"(d) : "v"(a), "v"(b));
    return d;
#endif
}

// async global->LDS DMA, 16B per lane. LDS dest must be wave-uniform base +
// lane*16 in lane order (m104/m108) — caller guarantees the mapping.
__device__ __forceinline__ void load16_lds(const u16* g, u16* l) {
    __builtin_amdgcn_global_load_lds(
        (const __attribute__((address_space(1))) u32*)g,
        (__attribute__((address_space(3))) u32*)l, 16, 0, 0);
}

// ---------------------------------------------------------------------------
// 32x32 transpose+convert tile body: out[c0+rr][r0+cc] = in[r0+cc][c0+rr]
// ---------------------------------------------------------------------------
__device__ __forceinline__ void tr_tile(const float* __restrict__ src,
                                        u16* __restrict__ dst,
                                        int R, int C, int r0, int c0, int tid) {
    __shared__ float tile[32][33];
    int cc = tid & 31, rr0 = tid >> 5;
#pragma unroll
    for (int s = 0; s < 4; ++s) {
        int rr = rr0 + s * 8;
        tile[rr][cc] = src[(size_t)(r0 + rr) * C + c0 + cc];
    }
    __syncthreads();
#pragma unroll
    for (int s = 0; s < 4; ++s) {
        int rr = rr0 + s * 8;
        dst[(size_t)(c0 + rr) * R + (r0 + cc)] = f2bf(tile[cc][rr]);
    }
}

// generic: in[R][C] f32 -> out[C][R] bf16, grid (C/32, R/32)
__global__ __launch_bounds__(256) void transpose_cvt(const float* __restrict__ in,
                                                     u16* __restrict__ out, int R, int C) {
    tr_tile(in, out, R, C, blockIdx.y * 32, blockIdx.x * 32, threadIdx.x);
}

// fused per-layer weight transpose: all 4 matrices of layer l, grid 1728
__global__ __launch_bounds__(256) void transpose_layer(const float* __restrict__ attn_w,
                                                       const float* __restrict__ proj_w,
                                                       const float* __restrict__ fc_w,
                                                       const float* __restrict__ fc2_w,
                                                       u16* __restrict__ wqkv,
                                                       u16* __restrict__ wproj,
                                                       u16* __restrict__ wfc,
                                                       u16* __restrict__ wfc2t,
                                                       int l) {
    int t = blockIdx.x;
    const float* src; u16* dst; int R, C, tx, ty;
    if (t < 432)       { int i = t;        src = attn_w + (size_t)l * 384 * 1152; dst = wqkv;  R = 384;  C = 1152; tx = i % 36; ty = i / 36; }
    else if (t < 576)  { int i = t - 432;  src = proj_w + (size_t)l * 384 * 384;  dst = wproj; R = 384;  C = 384;  tx = i % 12; ty = i / 12; }
    else if (t < 1152) { int i = t - 576;  src = fc_w   + (size_t)l * 384 * 1536; dst = wfc;   R = 384;  C = 1536; tx = i % 48; ty = i / 48; }
    else               { int i = t - 1152; src = fc2_w  + (size_t)l * 1536 * 384; dst = wfc2t; R = 1536; C = 384;  tx = i % 12; ty = i / 12; }
    tr_tile(src, dst, R, C, ty * 32, tx * 32, threadIdx.x);
}

// ---------------------------------------------------------------------------
// bf16 MFMA GEMM:  C[M,N] = A[M,K] @ B[K,N]
// A row-major bf16 (row stride K), BT row-major bf16 [N][ldb] (B^T slice).
// Tile 128x128, BK=64, 256 threads (4 waves = 2x2 of 64x64, each 4x4 MFMA).
// LDS: unpadded [128][64] via global_load_lds, 3-bit XOR col-group swizzle.
// XCD-chunked bijective blockIdx swizzle (T1/m204) for A-panel L2 locality.
// K must be a multiple of 64.
// MODE 0: out bf16 = acc+bias        MODE 1: out bf16 = gelu(acc+bias)
// MODE 2: out f32  = resid+acc+bias  MODE 3: out f32  = acc+bias
// out row stride = N. grid (N/128, ceil(M/128))
// ---------------------------------------------------------------------------
template<int MODE>
__global__ __launch_bounds__(256) void gemm_bt(const u16* __restrict__ A,
                                               const u16* __restrict__ BT, int ldb,
                                               const float* __restrict__ bias,
                                               void* __restrict__ out,
                                               const float* __restrict__ resid,
                                               int N, int K) {
    __shared__ u16 As[128 * 64];   // 16 KB
    __shared__ u16 Bs[128 * 64];   // 16 KB
    int tid = threadIdx.x;
    int lane = tid & 63, wave = tid >> 6;
    int wr = wave >> 1, wc = wave & 1;

    // ---- XCD-chunked bijective block swizzle (m204) ----
    int nwg  = gridDim.x * gridDim.y;
    int orig = blockIdx.y * gridDim.x + blockIdx.x;
    int qq = nwg >> 3, rr = nwg & 7;
    int xcd = orig & 7, idx0 = orig >> 3;
    int wg = (xcd < rr ? xcd * (qq + 1) : rr * (qq + 1) + (xcd - rr) * qq) + idx0;
    int bx = wg % gridDim.x, by = wg / gridDim.x;

    const u16* Ab = A  + (size_t)by * 128 * K;
    const u16* Bb = BT + (size_t)bx * 128 * ldb;

    f32x4 acc[4][4];
#pragma unroll
    for (int i = 0; i < 4; ++i)
#pragma unroll
        for (int j = 0; j < 4; ++j)
#pragma unroll
            for (int r = 0; r < 4; ++r) acc[i][j][r] = 0.f;

    int r16  = lane & 15;
    int quad = lane >> 4;
    int sw   = r16 & 7;

    // staging map: seg in [0,1024), 16B each; row = seg>>3, LDS slot cg = seg&7
    // holds global col-group (seg&7) ^ (row&7).
    int srow[4], scol[4];
#pragma unroll
    for (int s = 0; s < 4; ++s) {
        int seg = s * 256 + tid;
        srow[s] = seg >> 3;
        scol[s] = (((seg & 7) ^ (srow[s] & 7)) << 3);
    }

    for (int kt = 0; kt < K; kt += 64) {
#pragma unroll
        for (int s = 0; s < 4; ++s) {
            int seg = s * 256 + tid;
            load16_lds(Ab + (size_t)srow[s] * K   + kt + scol[s], &As[seg * 8]);
            load16_lds(Bb + (size_t)srow[s] * ldb + kt + scol[s], &Bs[seg * 8]);
        }
        __syncthreads();
#pragma unroll
        for (int kk = 0; kk < 2; ++kk) {     // k-offsets 0, 32 within the 64-slice
            bf16x8 af[4], bff[4];
#pragma unroll
            for (int i = 0; i < 4; ++i) {
                int cg = ((kk * 4 + quad) ^ sw) << 3;
                af[i]  = *(const bf16x8*)&As[(wr * 64 + i * 16 + r16) * 64 + cg];
                bff[i] = *(const bf16x8*)&Bs[(wc * 64 + i * 16 + r16) * 64 + cg];
            }
#pragma unroll
            for (int i = 0; i < 4; ++i)
#pragma unroll
                for (int j = 0; j < 4; ++j)
                    acc[i][j] = __builtin_amdgcn_mfma_f32_16x16x32_bf16(af[i], bff[j], acc[i][j], 0, 0, 0);
        }
        __syncthreads();
    }

    int rbase = (lane >> 4) * 4;
#pragma unroll
    for (int i = 0; i < 4; ++i) {
#pragma unroll
        for (int j = 0; j < 4; ++j) {
            int gr0 = by * 128 + wr * 64 + i * 16 + rbase;
            int gc  = bx * 128 + wc * 64 + j * 16 + (lane & 15);
            float bj = bias ? bias[gc] : 0.f;
#pragma unroll
            for (int r = 0; r < 4; ++r) {
                size_t idx = (size_t)(gr0 + r) * N + gc;
                float v = acc[i][j][r] + bj;
                if (MODE == 0)      ((u16*)out)[idx] = f2bf(v);
                else if (MODE == 1) ((u16*)out)[idx] = f2bf(gelu_f(v));
                else if (MODE == 2) ((float*)out)[idx] = resid[idx] + v;
                else                ((float*)out)[idx] = v;
            }
        }
    }
}

// ---------------------------------------------------------------------------
// LayerNorm: rows of 384 f32 -> 384 (bf16 or f32). block 256 = 4 waves,
// one row per wave. input row = row*inRowMul + inRowAdd, output row = row
// ---------------------------------------------------------------------------
template<bool BF16OUT>
__global__ __launch_bounds__(256) void ln_kernel(const float* __restrict__ x,
                                                 const float* __restrict__ w,
                                                 const float* __restrict__ b,
                                                 void* __restrict__ yout,
                                                 int inRowMul, int inRowAdd, int nRows) {
    int row = blockIdx.x * 4 + (threadIdx.x >> 6);
    if (row >= nRows) return;
    const float* xr = x + ((size_t)row * inRowMul + inRowAdd) * N_EMBD;
    int lane = threadIdx.x & 63;
    float v[6], s = 0.f, s2 = 0.f;
#pragma unroll
    for (int i = 0; i < 6; ++i) {
        v[i] = xr[lane + 64 * i];
        s += v[i]; s2 += v[i] * v[i];
    }
#pragma unroll
    for (int off = 32; off > 0; off >>= 1) {
        s  += __shfl_down(s, off);
        s2 += __shfl_down(s2, off);
    }
    float mean = __shfl(s, 0) * (1.f / 384.f);
    float var  = __shfl(s2, 0) * (1.f / 384.f) - mean * mean;
    float rs = rsqrtf(var + 1e-5f);
#pragma unroll
    for (int i = 0; i < 6; ++i) {
        int c = lane + 64 * i;
        float o = (v[i] - mean) * rs * w[c] + b[c];
        if (BF16OUT) ((u16*)yout)[(size_t)row * N_EMBD + c] = f2bf(o);
        else         ((float*)yout)[(size_t)row * N_EMBD + c] = o;
    }
}

// ---------------------------------------------------------------------------
// MFMA attention v5b: register-P + two-chunk online softmax, NaN-fixed (R13).
//
// R12 post-mortem: v5 NaN'd. Root cause: for the readout row q=290, chunk 0
// (keys 0..159) is ENTIRELY masked. With mask=-1e30 the chunk max m=-1e30,
// and p = exp2(fma(s*C) - round(m*C)) at s==m==-1e30 is a catastrophic
// cancellation of ~1.8e29 magnitudes: fma residue up to ~1e22 ->
// exp2(+1e22)=inf -> l=inf -> inf*0=NaN at the chunk-1 rescale. v4
// (monolithic max) never saw an all-masked max, so -1e30 was safe there.
// v5b: mask sentinel = -30000.0f (real raw scores are O(10); margin 3000x).
// All-masked chunk now gives m=-3e4, p≈1 junk (fma residue ~3e-4), and the
// chunk-1 rescale multiplies l/of by exp2((-30000-m_real)*C)=0 -> junk
// exactly cancelled (standard flash-attention property). Normal rows: masked
// keys underflow to 0 as before. No other change from v5.
// ---------------------------------------------------------------------------
#define SMASK -30000.0f

template<int KT0, int NKT>
__device__ __forceinline__ void attn_chunk(const u16* __restrict__ Ks,
                                           const u16* __restrict__ Vt,
                                           bf16x8 qf0, bf16x8 qf1,
                                           int quad, int ln, int sw, int qt, int q,
                                           float& m, float& l, f32x4 of[4]) {
    const float C = 0.18033688011112042f;   // 0.125 * log2(e)
    f32x4 sc[NKT];
#pragma unroll
    for (int i = 0; i < NKT; ++i) {
        int kt = KT0 + i;
        const u16* kr = &Ks[(kt * 16 + ln) * 64];   // (row&7) == sw
        bf16x8 kb0 = *(const bf16x8*)&kr[(quad ^ sw) << 3];
        bf16x8 kb1 = *(const bf16x8*)&kr[((4 | quad) ^ sw) << 3];
        f32x4 z = {0.f, 0.f, 0.f, 0.f};
        z = __builtin_amdgcn_mfma_f32_16x16x32_bf16(kb0, qf0, z, 0, 0, 0);   // swapped
        sc[i] = __builtin_amdgcn_mfma_f32_16x16x32_bf16(kb1, qf1, z, 0, 0, 0);
    }
    // lane holds S[key = kt*16+quad*4+r][q] (raw, unscaled)

    float mc = SMASK;
    if (qt == 18) {
        // q-tile containing the readout row (q==290 attends only itself)
#pragma unroll
        for (int i = 0; i < NKT; ++i)
#pragma unroll
            for (int r = 0; r < 4; ++r) {
                int key = (KT0 + i) * 16 + quad * 4 + r;
                bool ok = (key < TT) && (q != TT - 1 || key == TT - 1);
                float s = ok ? sc[i][r] : SMASK;
                sc[i][r] = s;
                mc = fmaxf(mc, s);
            }
    } else {
#pragma unroll
        for (int i = 0; i < NKT; ++i) {
            if (KT0 + i == 18) {
#pragma unroll
                for (int r = 0; r < 4; ++r) {   // kt=18 spans keys 288..303
                    int key = 288 + quad * 4 + r;
                    float s = (key < TT) ? sc[i][r] : SMASK;
                    sc[i][r] = s;
                    mc = fmaxf(mc, s);
                }
            } else {
#pragma unroll
                for (int r = 0; r < 4; ++r) mc = fmaxf(mc, sc[i][r]);
            }
        }
    }
    mc = fmaxf(mc, __shfl_xor(mc, 16));
    mc = fmaxf(mc, __shfl_xor(mc, 32));

    if (KT0 == 0) {
        m = mc;                  // first chunk: of = 0, l = 0 — no rescale
    } else {
        float mn = fmaxf(m, mc);
        float sca = __builtin_amdgcn_exp2f((m - mn) * C);
        l *= sca;
        // of rows are q0+quad*4+r; their scale lives at lane ln=quad*4+r
        float scaq[4];
#pragma unroll
        for (int r = 0; r < 4; ++r) scaq[r] = __shfl(sca, quad * 4 + r);
#pragma unroll
        for (int nt = 0; nt < 4; ++nt)
#pragma unroll
            for (int r = 0; r < 4; ++r) of[nt][r] *= scaq[r];
        m = mn;
    }

    float mcC = m * C;
#pragma unroll
    for (int i = 0; i < NKT; ++i) {
        s16x4 pa;
#pragma unroll
        for (int r = 0; r < 4; ++r) {
            float p = __builtin_amdgcn_exp2f(fmaf(sc[i][r], C, -mcC));
            l += p;
            pa[r] = (short)f2bf(p);
        }
#pragma unroll
        for (int nt = 0; nt < 4; ++nt) {
            s16x4 vb = *(const s16x4*)&Vt[(nt * 16 + ln) * 328 + (KT0 + i) * 16 + quad * 4];
            of[nt] = mfma16(pa, vb, of[nt]);
        }
    }
}

__global__ __launch_bounds__(512, 2) void attn_mfma(const u16* __restrict__ qkv,
                                                    u16* __restrict__ o) {
    __shared__ __align__(16) u16 Ks[304 * 64];      // 38,912 B, swizzled
    __shared__ __align__(16) u16 Vt[64 * 328];      // 41,984 B
    int h = blockIdx.x, b = blockIdx.y;
    int tid = threadIdx.x;
    int lane = tid & 63, wave = tid >> 6;
    int ln = lane & 15, quad = lane >> 4;
    int sw = ln & 7;
    const u16* base = qkv + (size_t)b * TT * 1152;

    // ---- stage K rows 0..290 (+clamped pad rows 291..303) via DMA ----
    // chunk c: LDS group (c&7) holds global col-group (c&7)^(row&7).
    for (int c = tid; c < 304 * 8; c += 512) {
        int row = c >> 3;
        int g   = (c & 7) ^ (row & 7);
        int srow = row < TT ? row : TT - 1;
        load16_lds(base + (size_t)srow * 1152 + 384 + h * 64 + g * 8, &Ks[c * 8]);
    }
    // ---- stage V transposed: Vt[d][key] ----
    for (int s = tid; s < TT * 8; s += 512) {
        int dg = s / TT, k = s - dg * TT;
        uint4 v = *(const uint4*)(base + (size_t)k * 1152 + 768 + h * 64 + dg * 8);
        const u16* pv = (const u16*)&v;
#pragma unroll
        for (int j = 0; j < 8; ++j) Vt[(dg * 8 + j) * 328 + k] = pv[j];
    }
    // zero pad cols 291..327 of Vt (disjoint from staged cols, no race)
    for (int s = tid; s < 64 * 37; s += 512) {
        int d = s / 37, c2 = s - d * 37;
        Vt[d * 328 + TT + c2] = 0;
    }
    __syncthreads();

    // ---- per-wave Q-tiles (19 tiles over 8 waves) ----
    for (int qt = wave; qt < 19; qt += 8) {
        int q0 = qt * 16;
        int qrow = q0 + ln; if (qrow > TT - 1) qrow = TT - 1;
        const u16* qp = base + (size_t)qrow * 1152 + h * 64;
        bf16x8 qf0 = *(const bf16x8*)(qp + quad * 8);
        bf16x8 qf1 = *(const bf16x8*)(qp + 32 + quad * 8);
        int q = q0 + ln;

        float m = SMASK, l = 0.f;
        f32x4 of[4];
#pragma unroll
        for (int nt = 0; nt < 4; ++nt)
#pragma unroll
            for (int r = 0; r < 4; ++r) of[nt][r] = 0.f;

        attn_chunk<0, 10>(Ks, Vt, qf0, qf1, quad, ln, sw, qt, q, m, l, of);
        attn_chunk<10, 9>(Ks, Vt, qf0, qf1, quad, ln, sw, qt, q, m, l, of);

        l += __shfl_xor(l, 16);
        l += __shfl_xor(l, 32);
        float linv = 1.f / l;
        // linv for OUTPUT rows q0+quad*4+r lives at lane quad*4+r
        float linvq[4];
#pragma unroll
        for (int r = 0; r < 4; ++r) linvq[r] = __shfl(linv, quad * 4 + r);

#pragma unroll
        for (int nt = 0; nt < 4; ++nt)
#pragma unroll
            for (int r = 0; r < 4; ++r) {
                int qo = q0 + quad * 4 + r;
                if (qo < TT)
                    o[((size_t)(b * TT + qo)) * N_EMBD + h * 64 + nt * 16 + ln] =
                        f2bf(of[nt][r] * linvq[r]);
            }
    }
}

// ---------------------------------------------------------------------------
// Tokenizer helpers
// ---------------------------------------------------------------------------
__global__ __launch_bounds__(256) void patchify_kernel(const float* __restrict__ images,
                                                       u16* __restrict__ P) {
    int idx = blockIdx.x * 256 + threadIdx.x;  // 36864*192 exact
    int col = idx % 192, row = idx / 192;
    int p = row % 144, bt = row / 144;
    int c = col % 3, pp = col / 3;
    int pw = pp & 7, ph = pp >> 3;
    int hp = p / 12, wp = p % 12;
    float v = images[(((size_t)bt * 3 + c) * 96 + hp * 8 + ph) * 96 + wp * 8 + pw];
    P[idx] = f2bf(v);
}

__global__ __launch_bounds__(256) void img_scatter_kernel(const float* __restrict__ imgtok,
                                                          const float* __restrict__ temb,
                                                          const float* __restrict__ pos,
                                                          float* __restrict__ xw) {
    int idx = blockIdx.x * 256 + threadIdx.x;  // 36864*384 exact
    int n = idx % 384, row = idx / 384;
    int p = row % 144, bt = row / 144;
    int t = bt & 1, b = bt >> 1;
    int tok = t * 145 + 1 + p;
    xw[((size_t)b * TT + tok) * N_EMBD + n] =
        imgtok[idx] + temb[t * N_EMBD + n] + pos[(size_t)tok * N_EMBD + n];
}

__global__ __launch_bounds__(384) void st_kernel(const float* __restrict__ state,
                                                 const float* __restrict__ w1,
                                                 const float* __restrict__ b1,
                                                 const float* __restrict__ w2,
                                                 const float* __restrict__ b2,
                                                 const float* __restrict__ temb,
                                                 const float* __restrict__ pos,
                                                 float* __restrict__ xw) {
    int bt = blockIdx.x;
    int t = bt & 1, b = bt >> 1;
    int n = threadIdx.x;
    float s0 = state[bt * 2], s1 = state[bt * 2 + 1];
    float acc = b2[n];
#pragma unroll
    for (int j = 0; j < 32; ++j) {
        float hh = fmaxf(s0 * w1[j] + s1 * w1[32 + j] + b1[j], 0.f);
        acc += hh * w2[j * N_EMBD + n];
    }
    int tok = t * 145;
    xw[((size_t)b * TT + tok) * N_EMBD + n] =
        acc + temb[t * N_EMBD + n] + pos[(size_t)tok * N_EMBD + n];
}

__global__ __launch_bounds__(256) void ro_kernel(const float* __restrict__ readout,
                                                 const float* __restrict__ pos,
                                                 float* __restrict__ xw) {
    int idx = blockIdx.x * 256 + threadIdx.x;  // 128*384 exact
    int n = idx % 384, b = idx / 384;
    xw[((size_t)b * TT + 290) * N_EMBD + n] = readout[n] + pos[(size_t)290 * N_EMBD + n];
}

// ---------------------------------------------------------------------------
// Workspace layout (all offsets 256B-aligned). TOTAL = 175,325,184 B (~167 MB)
// ---------------------------------------------------------------------------
extern "C" void kernel_launch(void* const* d_in, const int* in_sizes, int n_in,
                              void* d_out, int out_size, void* d_ws, size_t ws_size,
                              hipStream_t stream) {
    const float* images   = (const float*)d_in[0];
    const float* state    = (const float*)d_in[1];
    const float* img_w    = (const float*)d_in[2];
    const float* img_b    = (const float*)d_in[3];
    const float* img_temb = (const float*)d_in[4];
    const float* st_w1    = (const float*)d_in[5];
    const float* st_b1    = (const float*)d_in[6];
    const float* st_w2    = (const float*)d_in[7];
    const float* st_b2    = (const float*)d_in[8];
    const float* st_temb  = (const float*)d_in[9];
    const float* readout  = (const float*)d_in[10];
    const float* pos      = (const float*)d_in[11];
    const float* ln1_w    = (const float*)d_in[12];
    const float* ln1_b    = (const float*)d_in[13];
    const float* attn_w   = (const float*)d_in[14];
    const float* attn_b   = (const float*)d_in[15];
    const float* proj_w   = (const float*)d_in[16];
    const float* proj_b   = (const float*)d_in[17];
    const float* ln2_w    = (const float*)d_in[18];
    const float* ln2_b    = (const float*)d_in[19];
    const float* fc_w     = (const float*)d_in[20];
    const float* fc_b     = (const float*)d_in[21];
    const float* fc2_w    = (const float*)d_in[22];
    const float* fc2_b    = (const float*)d_in[23];
    const float* lnf_w    = (const float*)d_in[24];
    const float* lnf_b    = (const float*)d_in[25];

    char* ws = (char*)d_ws;
    float* XW   = (float*)(ws);
    u16*   Y    = (u16*)(ws + 57212928ull);       // also O (attn output)
    u16*   SH   = (u16*)(ws + 85819392ull);       // QKV | G | setup
    u16*   QKV  = SH;
    u16*   G    = SH;
    u16*   P    = SH;                              // setup: patches [36864,192]
    float* IMGT = (float*)(ws + 85819392ull + 14155776ull);  // setup: [36864,384] f32
    u16*   WQKVl  = (u16*)(ws + 171638784ull);    // [1152][384]
    u16*   WPROJl = (u16*)(ws + 172523520ull);    // [384][384]
    u16*   WFCl   = (u16*)(ws + 172818432ull);    // [1536][384]
    u16*   WFC2Tl = (u16*)(ws + 173998080ull);    // [384][1536]
    u16*   WIMG   = (u16*)(ws + 175177728ull);    // [384][192]

    // ---- tokenizers -> XW [128*291, 384] f32 ----
    transpose_cvt<<<dim3(12, 6), 256, 0, stream>>>(img_w, WIMG, 192, 384);
    patchify_kernel<<<27648, 256, 0, stream>>>(images, P);
    gemm_bt<3><<<dim3(3, 288), 256, 0, stream>>>(P, WIMG, 192, img_b, IMGT, nullptr, 384, 192);
    img_scatter_kernel<<<55296, 256, 0, stream>>>(IMGT, img_temb, pos, XW);
    st_kernel<<<256, 384, 0, stream>>>(state, st_w1, st_b1, st_w2, st_b2, st_temb, pos, XW);
    ro_kernel<<<192, 256, 0, stream>>>(readout, pos, XW);

    // ---- transformer layers (M = 37248 = 128*291) ----
    // MLP is M-split (146 + 145 row-blocks): full-width G half fits the QKV
    // region and fc2 runs as ONE K=1536 GEMM per half (halves f32 resid traffic).
    const size_t M0 = 18688;   // 146 * 128
    for (int l = 0; l < 12; ++l) {
        transpose_layer<<<1728, 256, 0, stream>>>(attn_w, proj_w, fc_w, fc2_w,
                                                  WQKVl, WPROJl, WFCl, WFC2Tl, l);
        ln_kernel<true><<<9312, 256, 0, stream>>>(XW, ln1_w + l * 384, ln1_b + l * 384, Y, 1, 0, 37248);
        gemm_bt<0><<<dim3(9, 291), 256, 0, stream>>>(Y, WQKVl, 384, attn_b + l * 1152,
                                                     QKV, nullptr, 1152, 384);
        attn_mfma<<<dim3(6, 128), 512, 0, stream>>>(QKV, Y);   // O aliases Y
        gemm_bt<2><<<dim3(3, 291), 256, 0, stream>>>(Y, WPROJl, 384, proj_b + l * 384,
                                                     XW, XW, 384, 384);
        ln_kernel<true><<<9312, 256, 0, stream>>>(XW, ln2_w + l * 384, ln2_b + l * 384, Y, 1, 0, 37248);
        // MLP half 0: rows [0, 18688)
        gemm_bt<1><<<dim3(12, 146), 256, 0, stream>>>(Y, WFCl, 384, fc_b + l * 1536,
                                                      G, nullptr, 1536, 384);
        gemm_bt<2><<<dim3(3, 146), 256, 0, stream>>>(G, WFC2Tl, 1536, fc2_b + l * 384,
                                                     XW, XW, 384, 1536);
        // MLP half 1: rows [18688, 37248)
        gemm_bt<1><<<dim3(12, 145), 256, 0, stream>>>(Y + M0 * 384, WFCl, 384, fc_b + l * 1536,
                                                      G, nullptr, 1536, 384);
        gemm_bt<2><<<dim3(3, 145), 256, 0, stream>>>(G, WFC2Tl, 1536, fc2_b + l * 384,
                                                     XW + M0 * 384, XW + M0 * 384, 384, 1536);
    }
    // final LN on readout rows -> d_out [128, 384] f32
    ln_kernel<false><<<32, 256, 0, stream>>>(XW, lnf_w, lnf_b, d_out, TT, 290, 128);
}

// Round 8
// 5960.350 us; speedup vs baseline: 1.0050x; 1.0050x over previous
//
#include <hip/hip_runtime.h>

typedef unsigned short u16;
typedef unsigned int u32;

typedef __bf16 bf16x8 __attribute__((ext_vector_type(8)));
typedef float  f32x4  __attribute__((ext_vector_type(4)));
typedef short  s16x4  __attribute__((ext_vector_type(4)));

#define N_EMBD 384
#define TT     291
#define NB     128

__device__ __forceinline__ u16 f2bf(float x) {
    union { float f; u32 u; } v; v.f = x;
    u32 r = v.u + 0x7FFFu + ((v.u >> 16) & 1u);
    return (u16)(r >> 16);
}
__device__ __forceinline__ float bfl(u32 u) { return __uint_as_float(u << 16); }
__device__ __forceinline__ float bfh(u32 u) { return __uint_as_float(u & 0xFFFF0000u); }

__device__ __forceinline__ float gelu_f(float x) {
    float u = 0.7978845608028654f * x * (1.f + 0.044715f * x * x);
    float e = __expf(2.f * u);
    float t = 1.f - 2.f / (e + 1.f);   // tanh(u), safe at +-inf
    return 0.5f * x * (1.f + t);
}

// K=16 bf16 MFMA (PV step): A/B are 4 bf16 (2 VGPRs), C/D 4 f32.
__device__ __forceinline__ f32x4 mfma16(s16x4 a, s16x4 b, f32x4 c) {
#if __has_builtin(__builtin_amdgcn_mfma_f32_16x16x16bf16_1k)
    return __builtin_amdgcn_mfma_f32_16x16x16bf16_1k(a, b, c, 0, 0, 0);
#elif __has_builtin(__builtin_amdgcn_mfma_f32_16x16x16_bf16)
    typedef __bf16 bf16x4v __attribute__((ext_vector_type(4)));
    return __builtin_amdgcn_mfma_f32_16x16x16_bf16(__builtin_bit_cast(bf16x4v, a),
                                                   __builtin_bit_cast(bf16x4v, b), c, 0, 0, 0);
#else
    f32x4 d = c;
    asm("v_mfma_f32_16x16x16_bf16 %0, %1, %2, %0" : "+v"(d) : "v"(a), "v"(b));
    return d;
#endif
}

// async global->LDS DMA, 16B per lane. LDS dest must be wave-uniform base +
// lane*16 in lane order (m104/m108) — caller guarantees the mapping.
__device__ __forceinline__ void load16_lds(const u16* g, u16* l) {
    __builtin_amdgcn_global_load_lds(
        (const __attribute__((address_space(1))) u32*)g,
        (__attribute__((address_space(3))) u32*)l, 16, 0, 0);
}

// ---------------------------------------------------------------------------
// 32x32 transpose+convert tile body: out[c0+rr][r0+cc] = in[r0+cc][c0+rr]
// ---------------------------------------------------------------------------
__device__ __forceinline__ void tr_tile(const float* __restrict__ src,
                                        u16* __restrict__ dst,
                                        int R, int C, int r0, int c0, int tid) {
    __shared__ float tile[32][33];
    int cc = tid & 31, rr0 = tid >> 5;
#pragma unroll
    for (int s = 0; s < 4; ++s) {
        int rr = rr0 + s * 8;
        tile[rr][cc] = src[(size_t)(r0 + rr) * C + c0 + cc];
    }
    __syncthreads();
#pragma unroll
    for (int s = 0; s < 4; ++s) {
        int rr = rr0 + s * 8;
        dst[(size_t)(c0 + rr) * R + (r0 + cc)] = f2bf(tile[cc][rr]);
    }
}

// generic: in[R][C] f32 -> out[C][R] bf16, grid (C/32, R/32)
__global__ __launch_bounds__(256) void transpose_cvt(const float* __restrict__ in,
                                                     u16* __restrict__ out, int R, int C) {
    tr_tile(in, out, R, C, blockIdx.y * 32, blockIdx.x * 32, threadIdx.x);
}

// fused per-layer weight transpose: all 4 matrices of layer l, grid 1728
__global__ __launch_bounds__(256) void transpose_layer(const float* __restrict__ attn_w,
                                                       const float* __restrict__ proj_w,
                                                       const float* __restrict__ fc_w,
                                                       const float* __restrict__ fc2_w,
                                                       u16* __restrict__ wqkv,
                                                       u16* __restrict__ wproj,
                                                       u16* __restrict__ wfc,
                                                       u16* __restrict__ wfc2t,
                                                       int l) {
    int t = blockIdx.x;
    const float* src; u16* dst; int R, C, tx, ty;
    if (t < 432)       { int i = t;        src = attn_w + (size_t)l * 384 * 1152; dst = wqkv;  R = 384;  C = 1152; tx = i % 36; ty = i / 36; }
    else if (t < 576)  { int i = t - 432;  src = proj_w + (size_t)l * 384 * 384;  dst = wproj; R = 384;  C = 384;  tx = i % 12; ty = i / 12; }
    else if (t < 1152) { int i = t - 576;  src = fc_w   + (size_t)l * 384 * 1536; dst = wfc;   R = 384;  C = 1536; tx = i % 48; ty = i / 48; }
    else               { int i = t - 1152; src = fc2_w  + (size_t)l * 1536 * 384; dst = wfc2t; R = 1536; C = 384;  tx = i % 12; ty = i / 12; }
    tr_tile(src, dst, R, C, ty * 32, tx * 32, threadIdx.x);
}

// ---------------------------------------------------------------------------
// bf16 MFMA GEMM:  C[M,N] = A[M,K] @ B[K,N]
// A row-major bf16 (row stride K), BT row-major bf16 [N][ldb] (B^T slice).
// Tile 128x128, BK=64, 256 threads (4 waves = 2x2 of 64x64, each 4x4 MFMA).
// LDS: unpadded [128][64] via global_load_lds, 3-bit XOR col-group swizzle.
// XCD-chunked bijective blockIdx swizzle (T1/m204) for A-panel L2 locality.
// K must be a multiple of 64.
// MODE 0: out bf16 = acc+bias        MODE 1: out bf16 = gelu(acc+bias)
// MODE 2: out f32  = resid+acc+bias  MODE 3: out f32  = acc+bias
// out row stride = N. grid (N/128, ceil(M/128))
// ---------------------------------------------------------------------------
template<int MODE>
__global__ __launch_bounds__(256) void gemm_bt(const u16* __restrict__ A,
                                               const u16* __restrict__ BT, int ldb,
                                               const float* __restrict__ bias,
                                               void* __restrict__ out,
                                               const float* __restrict__ resid,
                                               int N, int K) {
    __shared__ u16 As[128 * 64];   // 16 KB
    __shared__ u16 Bs[128 * 64];   // 16 KB
    int tid = threadIdx.x;
    int lane = tid & 63, wave = tid >> 6;
    int wr = wave >> 1, wc = wave & 1;

    // ---- XCD-chunked bijective block swizzle (m204) ----
    int nwg  = gridDim.x * gridDim.y;
    int orig = blockIdx.y * gridDim.x + blockIdx.x;
    int qq = nwg >> 3, rr = nwg & 7;
    int xcd = orig & 7, idx0 = orig >> 3;
    int wg = (xcd < rr ? xcd * (qq + 1) : rr * (qq + 1) + (xcd - rr) * qq) + idx0;
    int bx = wg % gridDim.x, by = wg / gridDim.x;

    const u16* Ab = A  + (size_t)by * 128 * K;
    const u16* Bb = BT + (size_t)bx * 128 * ldb;

    f32x4 acc[4][4];
#pragma unroll
    for (int i = 0; i < 4; ++i)
#pragma unroll
        for (int j = 0; j < 4; ++j)
#pragma unroll
            for (int r = 0; r < 4; ++r) acc[i][j][r] = 0.f;

    int r16  = lane & 15;
    int quad = lane >> 4;
    int sw   = r16 & 7;

    // staging map: seg in [0,1024), 16B each; row = seg>>3, LDS slot cg = seg&7
    // holds global col-group (seg&7) ^ (row&7).
    int srow[4], scol[4];
#pragma unroll
    for (int s = 0; s < 4; ++s) {
        int seg = s * 256 + tid;
        srow[s] = seg >> 3;
        scol[s] = (((seg & 7) ^ (srow[s] & 7)) << 3);
    }

    for (int kt = 0; kt < K; kt += 64) {
#pragma unroll
        for (int s = 0; s < 4; ++s) {
            int seg = s * 256 + tid;
            load16_lds(Ab + (size_t)srow[s] * K   + kt + scol[s], &As[seg * 8]);
            load16_lds(Bb + (size_t)srow[s] * ldb + kt + scol[s], &Bs[seg * 8]);
        }
        __syncthreads();
#pragma unroll
        for (int kk = 0; kk < 2; ++kk) {     // k-offsets 0, 32 within the 64-slice
            bf16x8 af[4], bff[4];
#pragma unroll
            for (int i = 0; i < 4; ++i) {
                int cg = ((kk * 4 + quad) ^ sw) << 3;
                af[i]  = *(const bf16x8*)&As[(wr * 64 + i * 16 + r16) * 64 + cg];
                bff[i] = *(const bf16x8*)&Bs[(wc * 64 + i * 16 + r16) * 64 + cg];
            }
#pragma unroll
            for (int i = 0; i < 4; ++i)
#pragma unroll
                for (int j = 0; j < 4; ++j)
                    acc[i][j] = __builtin_amdgcn_mfma_f32_16x16x32_bf16(af[i], bff[j], acc[i][j], 0, 0, 0);
        }
        __syncthreads();
    }

    int rbase = (lane >> 4) * 4;
#pragma unroll
    for (int i = 0; i < 4; ++i) {
#pragma unroll
        for (int j = 0; j < 4; ++j) {
            int gr0 = by * 128 + wr * 64 + i * 16 + rbase;
            int gc  = bx * 128 + wc * 64 + j * 16 + (lane & 15);
            float bj = bias ? bias[gc] : 0.f;
#pragma unroll
            for (int r = 0; r < 4; ++r) {
                size_t idx = (size_t)(gr0 + r) * N + gc;
                float v = acc[i][j][r] + bj;
                if (MODE == 0)      ((u16*)out)[idx] = f2bf(v);
                else if (MODE == 1) ((u16*)out)[idx] = f2bf(gelu_f(v));
                else if (MODE == 2) ((float*)out)[idx] = resid[idx] + v;
                else                ((float*)out)[idx] = v;
            }
        }
    }
}

// ---------------------------------------------------------------------------
// LayerNorm: rows of 384 f32 -> 384 (bf16 or f32). block 256 = 4 waves,
// one row per wave. input row = row*inRowMul + inRowAdd, output row = row
// ---------------------------------------------------------------------------
template<bool BF16OUT>
__global__ __launch_bounds__(256) void ln_kernel(const float* __restrict__ x,
                                                 const float* __restrict__ w,
                                                 const float* __restrict__ b,
                                                 void* __restrict__ yout,
                                                 int inRowMul, int inRowAdd, int nRows) {
    int row = blockIdx.x * 4 + (threadIdx.x >> 6);
    if (row >= nRows) return;
    const float* xr = x + ((size_t)row * inRowMul + inRowAdd) * N_EMBD;
    int lane = threadIdx.x & 63;
    float v[6], s = 0.f, s2 = 0.f;
#pragma unroll
    for (int i = 0; i < 6; ++i) {
        v[i] = xr[lane + 64 * i];
        s += v[i]; s2 += v[i] * v[i];
    }
#pragma unroll
    for (int off = 32; off > 0; off >>= 1) {
        s  += __shfl_down(s, off);
        s2 += __shfl_down(s2, off);
    }
    float mean = __shfl(s, 0) * (1.f / 384.f);
    float var  = __shfl(s2, 0) * (1.f / 384.f) - mean * mean;
    float rs = rsqrtf(var + 1e-5f);
#pragma unroll
    for (int i = 0; i < 6; ++i) {
        int c = lane + 64 * i;
        float o = (v[i] - mean) * rs * w[c] + b[c];
        if (BF16OUT) ((u16*)yout)[(size_t)row * N_EMBD + c] = f2bf(o);
        else         ((float*)yout)[(size_t)row * N_EMBD + c] = o;
    }
}

// ---------------------------------------------------------------------------
// MFMA attention v6: register-P + FOUR-chunk online softmax (R14).
//
// R13 post-mortem: v5b (chunks 10+9) passed but spill was UNCHANGED vs v4
// (FETCH 347 vs 325 MB) -> sc[] was never the dominant spill source. Revised
// theory: pre-RA load hoisting. Chunk 0 exposes 20 independent ds_read_b128
// K-fragments (80 VGPR) and the fused PV loop exposes 40-76 independent
// ds_read_b64 V-fragments; the scheduler hoists them to hide LDS latency,
// then RA spills sc/of to fit. v4 and v5b spill identically because their
// PV window is identical.
// v6: chunks of 5,5,5,4 — per chunk only 10 K-frag loads (40 VGPR) then 20
// V-frag loads (40 VGPR); peak ~ max-phase(40) + sc[5](20) + of(16) + qf(8)
// + misc(~20) ~ 105 < 128. 3 rescales/qt extra (~75 VALU, noise).
// Mask sentinel -30000 (R13-verified) keeps all-masked chunks finite; the
// first real-max rescale multiplies junk l/of by exp2((SMASK-m_real)*C)=0.
// LDS 80,896 x 2 = 161,792 <= 163,840 -> 2 blocks/CU.
// ---------------------------------------------------------------------------
#define SMASK -30000.0f

template<int KT0, int NKT>
__device__ __forceinline__ void attn_chunk(const u16* __restrict__ Ks,
                                           const u16* __restrict__ Vt,
                                           bf16x8 qf0, bf16x8 qf1,
                                           int quad, int ln, int sw, int qt, int q,
                                           float& m, float& l, f32x4 of[4]) {
    const float C = 0.18033688011112042f;   // 0.125 * log2(e)
    f32x4 sc[NKT];
#pragma unroll
    for (int i = 0; i < NKT; ++i) {
        int kt = KT0 + i;
        const u16* kr = &Ks[(kt * 16 + ln) * 64];   // (row&7) == sw
        bf16x8 kb0 = *(const bf16x8*)&kr[(quad ^ sw) << 3];
        bf16x8 kb1 = *(const bf16x8*)&kr[((4 | quad) ^ sw) << 3];
        f32x4 z = {0.f, 0.f, 0.f, 0.f};
        z = __builtin_amdgcn_mfma_f32_16x16x32_bf16(kb0, qf0, z, 0, 0, 0);   // swapped
        sc[i] = __builtin_amdgcn_mfma_f32_16x16x32_bf16(kb1, qf1, z, 0, 0, 0);
    }
    // lane holds S[key = kt*16+quad*4+r][q] (raw, unscaled)

    float mc = SMASK;
    if (qt == 18) {
        // q-tile containing the readout row (q==290 attends only itself)
#pragma unroll
        for (int i = 0; i < NKT; ++i)
#pragma unroll
            for (int r = 0; r < 4; ++r) {
                int key = (KT0 + i) * 16 + quad * 4 + r;
                bool ok = (key < TT) && (q != TT - 1 || key == TT - 1);
                float s = ok ? sc[i][r] : SMASK;
                sc[i][r] = s;
                mc = fmaxf(mc, s);
            }
    } else {
#pragma unroll
        for (int i = 0; i < NKT; ++i) {
            if (KT0 + i == 18) {
#pragma unroll
                for (int r = 0; r < 4; ++r) {   // kt=18 spans keys 288..303
                    int key = 288 + quad * 4 + r;
                    float s = (key < TT) ? sc[i][r] : SMASK;
                    sc[i][r] = s;
                    mc = fmaxf(mc, s);
                }
            } else {
#pragma unroll
                for (int r = 0; r < 4; ++r) mc = fmaxf(mc, sc[i][r]);
            }
        }
    }
    mc = fmaxf(mc, __shfl_xor(mc, 16));
    mc = fmaxf(mc, __shfl_xor(mc, 32));

    if (KT0 == 0) {
        m = mc;                  // first chunk: of = 0, l = 0 — no rescale
    } else {
        float mn = fmaxf(m, mc);
        float sca = __builtin_amdgcn_exp2f((m - mn) * C);
        l *= sca;
        // of rows are q0+quad*4+r; their scale lives at lane ln=quad*4+r
        float scaq[4];
#pragma unroll
        for (int r = 0; r < 4; ++r) scaq[r] = __shfl(sca, quad * 4 + r);
#pragma unroll
        for (int nt = 0; nt < 4; ++nt)
#pragma unroll
            for (int r = 0; r < 4; ++r) of[nt][r] *= scaq[r];
        m = mn;
    }

    float mcC = m * C;
#pragma unroll
    for (int i = 0; i < NKT; ++i) {
        s16x4 pa;
#pragma unroll
        for (int r = 0; r < 4; ++r) {
            float p = __builtin_amdgcn_exp2f(fmaf(sc[i][r], C, -mcC));
            l += p;
            pa[r] = (short)f2bf(p);
        }
#pragma unroll
        for (int nt = 0; nt < 4; ++nt) {
            s16x4 vb = *(const s16x4*)&Vt[(nt * 16 + ln) * 328 + (KT0 + i) * 16 + quad * 4];
            of[nt] = mfma16(pa, vb, of[nt]);
        }
    }
}

__global__ __launch_bounds__(512, 2) void attn_mfma(const u16* __restrict__ qkv,
                                                    u16* __restrict__ o) {
    __shared__ __align__(16) u16 Ks[304 * 64];      // 38,912 B, swizzled
    __shared__ __align__(16) u16 Vt[64 * 328];      // 41,984 B
    int h = blockIdx.x, b = blockIdx.y;
    int tid = threadIdx.x;
    int lane = tid & 63, wave = tid >> 6;
    int ln = lane & 15, quad = lane >> 4;
    int sw = ln & 7;
    const u16* base = qkv + (size_t)b * TT * 1152;

    // ---- stage K rows 0..290 (+clamped pad rows 291..303) via DMA ----
    // chunk c: LDS group (c&7) holds global col-group (c&7)^(row&7).
    for (int c = tid; c < 304 * 8; c += 512) {
        int row = c >> 3;
        int g   = (c & 7) ^ (row & 7);
        int srow = row < TT ? row : TT - 1;
        load16_lds(base + (size_t)srow * 1152 + 384 + h * 64 + g * 8, &Ks[c * 8]);
    }
    // ---- stage V transposed: Vt[d][key] ----
    for (int s = tid; s < TT * 8; s += 512) {
        int dg = s / TT, k = s - dg * TT;
        uint4 v = *(const uint4*)(base + (size_t)k * 1152 + 768 + h * 64 + dg * 8);
        const u16* pv = (const u16*)&v;
#pragma unroll
        for (int j = 0; j < 8; ++j) Vt[(dg * 8 + j) * 328 + k] = pv[j];
    }
    // zero pad cols 291..327 of Vt (disjoint from staged cols, no race)
    for (int s = tid; s < 64 * 37; s += 512) {
        int d = s / 37, c2 = s - d * 37;
        Vt[d * 328 + TT + c2] = 0;
    }
    __syncthreads();

    // ---- per-wave Q-tiles (19 tiles over 8 waves) ----
    for (int qt = wave; qt < 19; qt += 8) {
        int q0 = qt * 16;
        int qrow = q0 + ln; if (qrow > TT - 1) qrow = TT - 1;
        const u16* qp = base + (size_t)qrow * 1152 + h * 64;
        bf16x8 qf0 = *(const bf16x8*)(qp + quad * 8);
        bf16x8 qf1 = *(const bf16x8*)(qp + 32 + quad * 8);
        int q = q0 + ln;

        float m = SMASK, l = 0.f;
        f32x4 of[4];
#pragma unroll
        for (int nt = 0; nt < 4; ++nt)
#pragma unroll
            for (int r = 0; r < 4; ++r) of[nt][r] = 0.f;

        attn_chunk<0,  5>(Ks, Vt, qf0, qf1, quad, ln, sw, qt, q, m, l, of);
        attn_chunk<5,  5>(Ks, Vt, qf0, qf1, quad, ln, sw, qt, q, m, l, of);
        attn_chunk<10, 5>(Ks, Vt, qf0, qf1, quad, ln, sw, qt, q, m, l, of);
        attn_chunk<15, 4>(Ks, Vt, qf0, qf1, quad, ln, sw, qt, q, m, l, of);

        l += __shfl_xor(l, 16);
        l += __shfl_xor(l, 32);
        float linv = 1.f / l;
        // linv for OUTPUT rows q0+quad*4+r lives at lane quad*4+r
        float linvq[4];
#pragma unroll
        for (int r = 0; r < 4; ++r) linvq[r] = __shfl(linv, quad * 4 + r);

#pragma unroll
        for (int nt = 0; nt < 4; ++nt)
#pragma unroll
            for (int r = 0; r < 4; ++r) {
                int qo = q0 + quad * 4 + r;
                if (qo < TT)
                    o[((size_t)(b * TT + qo)) * N_EMBD + h * 64 + nt * 16 + ln] =
                        f2bf(of[nt][r] * linvq[r]);
            }
    }
}

// ---------------------------------------------------------------------------
// Tokenizer helpers
// ---------------------------------------------------------------------------
__global__ __launch_bounds__(256) void patchify_kernel(const float* __restrict__ images,
                                                       u16* __restrict__ P) {
    int idx = blockIdx.x * 256 + threadIdx.x;  // 36864*192 exact
    int col = idx % 192, row = idx / 192;
    int p = row % 144, bt = row / 144;
    int c = col % 3, pp = col / 3;
    int pw = pp & 7, ph = pp >> 3;
    int hp = p / 12, wp = p % 12;
    float v = images[(((size_t)bt * 3 + c) * 96 + hp * 8 + ph) * 96 + wp * 8 + pw];
    P[idx] = f2bf(v);
}

__global__ __launch_bounds__(256) void img_scatter_kernel(const float* __restrict__ imgtok,
                                                          const float* __restrict__ temb,
                                                          const float* __restrict__ pos,
                                                          float* __restrict__ xw) {
    int idx = blockIdx.x * 256 + threadIdx.x;  // 36864*384 exact
    int n = idx % 384, row = idx / 384;
    int p = row % 144, bt = row / 144;
    int t = bt & 1, b = bt >> 1;
    int tok = t * 145 + 1 + p;
    xw[((size_t)b * TT + tok) * N_EMBD + n] =
        imgtok[idx] + temb[t * N_EMBD + n] + pos[(size_t)tok * N_EMBD + n];
}

__global__ __launch_bounds__(384) void st_kernel(const float* __restrict__ state,
                                                 const float* __restrict__ w1,
                                                 const float* __restrict__ b1,
                                                 const float* __restrict__ w2,
                                                 const float* __restrict__ b2,
                                                 const float* __restrict__ temb,
                                                 const float* __restrict__ pos,
                                                 float* __restrict__ xw) {
    int bt = blockIdx.x;
    int t = bt & 1, b = bt >> 1;
    int n = threadIdx.x;
    float s0 = state[bt * 2], s1 = state[bt * 2 + 1];
    float acc = b2[n];
#pragma unroll
    for (int j = 0; j < 32; ++j) {
        float hh = fmaxf(s0 * w1[j] + s1 * w1[32 + j] + b1[j], 0.f);
        acc += hh * w2[j * N_EMBD + n];
    }
    int tok = t * 145;
    xw[((size_t)b * TT + tok) * N_EMBD + n] =
        acc + temb[t * N_EMBD + n] + pos[(size_t)tok * N_EMBD + n];
}

__global__ __launch_bounds__(256) void ro_kernel(const float* __restrict__ readout,
                                                 const float* __restrict__ pos,
                                                 float* __restrict__ xw) {
    int idx = blockIdx.x * 256 + threadIdx.x;  // 128*384 exact
    int n = idx % 384, b = idx / 384;
    xw[((size_t)b * TT + 290) * N_EMBD + n] = readout[n] + pos[(size_t)290 * N_EMBD + n];
}

// ---------------------------------------------------------------------------
// Workspace layout (all offsets 256B-aligned). TOTAL = 175,325,184 B (~167 MB)
// ---------------------------------------------------------------------------
extern "C" void kernel_launch(void* const* d_in, const int* in_sizes, int n_in,
                              void* d_out, int out_size, void* d_ws, size_t ws_size,
                              hipStream_t stream) {
    const float* images   = (const float*)d_in[0];
    const float* state    = (const float*)d_in[1];
    const float* img_w    = (const float*)d_in[2];
    const float* img_b    = (const float*)d_in[3];
    const float* img_temb = (const float*)d_in[4];
    const float* st_w1    = (const float*)d_in[5];
    const float* st_b1    = (const float*)d_in[6];
    const float* st_w2    = (const float*)d_in[7];
    const float* st_b2    = (const float*)d_in[8];
    const float* st_temb  = (const float*)d_in[9];
    const float* readout  = (const float*)d_in[10];
    const float* pos      = (const float*)d_in[11];
    const float* ln1_w    = (const float*)d_in[12];
    const float* ln1_b    = (const float*)d_in[13];
    const float* attn_w   = (const float*)d_in[14];
    const float* attn_b   = (const float*)d_in[15];
    const float* proj_w   = (const float*)d_in[16];
    const float* proj_b   = (const float*)d_in[17];
    const float* ln2_w    = (const float*)d_in[18];
    const float* ln2_b    = (const float*)d_in[19];
    const float* fc_w     = (const float*)d_in[20];
    const float* fc_b     = (const float*)d_in[21];
    const float* fc2_w    = (const float*)d_in[22];
    const float* fc2_b    = (const float*)d_in[23];
    const float* lnf_w    = (const float*)d_in[24];
    const float* lnf_b    = (const float*)d_in[25];

    char* ws = (char*)d_ws;
    float* XW   = (float*)(ws);
    u16*   Y    = (u16*)(ws + 57212928ull);       // also O (attn output)
    u16*   SH   = (u16*)(ws + 85819392ull);       // QKV | G | setup
    u16*   QKV  = SH;
    u16*   G    = SH;
    u16*   P    = SH;                              // setup: patches [36864,192]
    float* IMGT = (float*)(ws + 85819392ull + 14155776ull);  // setup: [36864,384] f32
    u16*   WQKVl  = (u16*)(ws + 171638784ull);    // [1152][384]
    u16*   WPROJl = (u16*)(ws + 172523520ull);    // [384][384]
    u16*   WFCl   = (u16*)(ws + 172818432ull);    // [1536][384]
    u16*   WFC2Tl = (u16*)(ws + 173998080ull);    // [384][1536]
    u16*   WIMG   = (u16*)(ws + 175177728ull);    // [384][192]

    // ---- tokenizers -> XW [128*291, 384] f32 ----
    transpose_cvt<<<dim3(12, 6), 256, 0, stream>>>(img_w, WIMG, 192, 384);
    patchify_kernel<<<27648, 256, 0, stream>>>(images, P);
    gemm_bt<3><<<dim3(3, 288), 256, 0, stream>>>(P, WIMG, 192, img_b, IMGT, nullptr, 384, 192);
    img_scatter_kernel<<<55296, 256, 0, stream>>>(IMGT, img_temb, pos, XW);
    st_kernel<<<256, 384, 0, stream>>>(state, st_w1, st_b1, st_w2, st_b2, st_temb, pos, XW);
    ro_kernel<<<192, 256, 0, stream>>>(readout, pos, XW);

    // ---- transformer layers (M = 37248 = 128*291) ----
    // MLP is M-split (146 + 145 row-blocks): full-width G half fits the QKV
    // region and fc2 runs as ONE K=1536 GEMM per half (halves f32 resid traffic).
    const size_t M0 = 18688;   // 146 * 128
    for (int l = 0; l < 12; ++l) {
        transpose_layer<<<1728, 256, 0, stream>>>(attn_w, proj_w, fc_w, fc2_w,
                                                  WQKVl, WPROJl, WFCl, WFC2Tl, l);
        ln_kernel<true><<<9312, 256, 0, stream>>>(XW, ln1_w + l * 384, ln1_b + l * 384, Y, 1, 0, 37248);
        gemm_bt<0><<<dim3(9, 291), 256, 0, stream>>>(Y, WQKVl, 384, attn_b + l * 1152,
                                                     QKV, nullptr, 1152, 384);
        attn_mfma<<<dim3(6, 128), 512, 0, stream>>>(QKV, Y);   // O aliases Y
        gemm_bt<2><<<dim3(3, 291), 256, 0, stream>>>(Y, WPROJl, 384, proj_b + l * 384,
                                                     XW, XW, 384, 384);
        ln_kernel<true><<<9312, 256, 0, stream>>>(XW, ln2_w + l * 384, ln2_b + l * 384, Y, 1, 0, 37248);
        // MLP half 0: rows [0, 18688)
        gemm_bt<1><<<dim3(12, 146), 256, 0, stream>>>(Y, WFCl, 384, fc_b + l * 1536,
                                                      G, nullptr, 1536, 384);
        gemm_bt<2><<<dim3(3, 146), 256, 0, stream>>>(G, WFC2Tl, 1536, fc2_b + l * 384,
                                                     XW, XW, 384, 1536);
        // MLP half 1: rows [18688, 37248)
        gemm_bt<1><<<dim3(12, 145), 256, 0, stream>>>(Y + M0 * 384, WFCl, 384, fc_b + l * 1536,
                                                      G, nullptr, 1536, 384);
        gemm_bt<2><<<dim3(3, 145), 256, 0, stream>>>(G, WFC2Tl, 1536, fc2_b + l * 384,
                                                     XW + M0 * 384, XW + M0 * 384, 384, 1536);
    }
    // final LN on readout rows -> d_out [128, 384] f32
    ln_kernel<false><<<32, 256, 0, stream>>>(XW, lnf_w, lnf_b, d_out, TT, 290, 128);
}

// Round 9
// 4383.023 us; speedup vs baseline: 1.3667x; 1.3599x over previous
//
#include <hip/hip_runtime.h>

typedef unsigned short u16;
typedef unsigned int u32;

typedef __bf16 bf16x8 __attribute__((ext_vector_type(8)));
typedef float  f32x4  __attribute__((ext_vector_type(4)));

#define N_EMBD 384
#define TT     291
#define NB     128

__device__ __forceinline__ u16 f2bf(float x) {
    union { float f; u32 u; } v; v.f = x;
    u32 r = v.u + 0x7FFFu + ((v.u >> 16) & 1u);
    return (u16)(r >> 16);
}
__device__ __forceinline__ float bfl(u32 u) { return __uint_as_float(u << 16); }
__device__ __forceinline__ float bfh(u32 u) { return __uint_as_float(u & 0xFFFF0000u); }

__device__ __forceinline__ float gelu_f(float x) {
    float u = 0.7978845608028654f * x * (1.f + 0.044715f * x * x);
    float e = __expf(2.f * u);
    float t = 1.f - 2.f / (e + 1.f);   // tanh(u), safe at +-inf
    return 0.5f * x * (1.f + t);
}

// async global->LDS DMA, 16B per lane. LDS dest must be wave-uniform base +
// lane*16 in lane order (m104/m108) — caller guarantees the mapping.
__device__ __forceinline__ void load16_lds(const u16* g, u16* l) {
    __builtin_amdgcn_global_load_lds(
        (const __attribute__((address_space(1))) u32*)g,
        (__attribute__((address_space(3))) u32*)l, 16, 0, 0);
}

// ---------------------------------------------------------------------------
// 32x32 transpose+convert tile body: out[c0+rr][r0+cc] = in[r0+cc][c0+rr]
// ---------------------------------------------------------------------------
__device__ __forceinline__ void tr_tile(const float* __restrict__ src,
                                        u16* __restrict__ dst,
                                        int R, int C, int r0, int c0, int tid) {
    __shared__ float tile[32][33];
    int cc = tid & 31, rr0 = tid >> 5;
#pragma unroll
    for (int s = 0; s < 4; ++s) {
        int rr = rr0 + s * 8;
        tile[rr][cc] = src[(size_t)(r0 + rr) * C + c0 + cc];
    }
    __syncthreads();
#pragma unroll
    for (int s = 0; s < 4; ++s) {
        int rr = rr0 + s * 8;
        dst[(size_t)(c0 + rr) * R + (r0 + cc)] = f2bf(tile[cc][rr]);
    }
}

// generic: in[R][C] f32 -> out[C][R] bf16, grid (C/32, R/32)
__global__ __launch_bounds__(256) void transpose_cvt(const float* __restrict__ in,
                                                     u16* __restrict__ out, int R, int C) {
    tr_tile(in, out, R, C, blockIdx.y * 32, blockIdx.x * 32, threadIdx.x);
}

// fused per-layer weight transpose: all 4 matrices of layer l, grid 1728
__global__ __launch_bounds__(256) void transpose_layer(const float* __restrict__ attn_w,
                                                       const float* __restrict__ proj_w,
                                                       const float* __restrict__ fc_w,
                                                       const float* __restrict__ fc2_w,
                                                       u16* __restrict__ wqkv,
                                                       u16* __restrict__ wproj,
                                                       u16* __restrict__ wfc,
                                                       u16* __restrict__ wfc2t,
                                                       int l) {
    int t = blockIdx.x;
    const float* src; u16* dst; int R, C, tx, ty;
    if (t < 432)       { int i = t;        src = attn_w + (size_t)l * 384 * 1152; dst = wqkv;  R = 384;  C = 1152; tx = i % 36; ty = i / 36; }
    else if (t < 576)  { int i = t - 432;  src = proj_w + (size_t)l * 384 * 384;  dst = wproj; R = 384;  C = 384;  tx = i % 12; ty = i / 12; }
    else if (t < 1152) { int i = t - 576;  src = fc_w   + (size_t)l * 384 * 1536; dst = wfc;   R = 384;  C = 1536; tx = i % 48; ty = i / 48; }
    else               { int i = t - 1152; src = fc2_w  + (size_t)l * 1536 * 384; dst = wfc2t; R = 1536; C = 384;  tx = i % 12; ty = i / 12; }
    tr_tile(src, dst, R, C, ty * 32, tx * 32, threadIdx.x);
}

// ---------------------------------------------------------------------------
// bf16 MFMA GEMM:  C[M,N] = A[M,K] @ B[K,N]
// A row-major bf16 (row stride K), BT row-major bf16 [N][ldb] (B^T slice).
// Tile 128x128, BK=64, 256 threads (4 waves = 2x2 of 64x64, each 4x4 MFMA).
// LDS: unpadded [128][64] via global_load_lds, 3-bit XOR col-group swizzle.
// XCD-chunked bijective blockIdx swizzle (T1/m204) for A-panel L2 locality.
// K must be a multiple of 64.
// MODE 0: out bf16 = acc+bias        MODE 1: out bf16 = gelu(acc+bias)
// MODE 2: out f32  = resid+acc+bias  MODE 3: out f32  = acc+bias
// out row stride = N. grid (N/128, ceil(M/128))
// ---------------------------------------------------------------------------
template<int MODE>
__global__ __launch_bounds__(256) void gemm_bt(const u16* __restrict__ A,
                                               const u16* __restrict__ BT, int ldb,
                                               const float* __restrict__ bias,
                                               void* __restrict__ out,
                                               const float* __restrict__ resid,
                                               int N, int K) {
    __shared__ u16 As[128 * 64];   // 16 KB
    __shared__ u16 Bs[128 * 64];   // 16 KB
    int tid = threadIdx.x;
    int lane = tid & 63, wave = tid >> 6;
    int wr = wave >> 1, wc = wave & 1;

    // ---- XCD-chunked bijective block swizzle (m204) ----
    int nwg  = gridDim.x * gridDim.y;
    int orig = blockIdx.y * gridDim.x + blockIdx.x;
    int qq = nwg >> 3, rr = nwg & 7;
    int xcd = orig & 7, idx0 = orig >> 3;
    int wg = (xcd < rr ? xcd * (qq + 1) : rr * (qq + 1) + (xcd - rr) * qq) + idx0;
    int bx = wg % gridDim.x, by = wg / gridDim.x;

    const u16* Ab = A  + (size_t)by * 128 * K;
    const u16* Bb = BT + (size_t)bx * 128 * ldb;

    f32x4 acc[4][4];
#pragma unroll
    for (int i = 0; i < 4; ++i)
#pragma unroll
        for (int j = 0; j < 4; ++j)
#pragma unroll
            for (int r = 0; r < 4; ++r) acc[i][j][r] = 0.f;

    int r16  = lane & 15;
    int quad = lane >> 4;
    int sw   = r16 & 7;

    // staging map: seg in [0,1024), 16B each; row = seg>>3, LDS slot cg = seg&7
    // holds global col-group (seg&7) ^ (row&7).
    int srow[4], scol[4];
#pragma unroll
    for (int s = 0; s < 4; ++s) {
        int seg = s * 256 + tid;
        srow[s] = seg >> 3;
        scol[s] = (((seg & 7) ^ (srow[s] & 7)) << 3);
    }

    for (int kt = 0; kt < K; kt += 64) {
#pragma unroll
        for (int s = 0; s < 4; ++s) {
            int seg = s * 256 + tid;
            load16_lds(Ab + (size_t)srow[s] * K   + kt + scol[s], &As[seg * 8]);
            load16_lds(Bb + (size_t)srow[s] * ldb + kt + scol[s], &Bs[seg * 8]);
        }
        __syncthreads();
#pragma unroll
        for (int kk = 0; kk < 2; ++kk) {     // k-offsets 0, 32 within the 64-slice
            bf16x8 af[4], bff[4];
#pragma unroll
            for (int i = 0; i < 4; ++i) {
                int cg = ((kk * 4 + quad) ^ sw) << 3;
                af[i]  = *(const bf16x8*)&As[(wr * 64 + i * 16 + r16) * 64 + cg];
                bff[i] = *(const bf16x8*)&Bs[(wc * 64 + i * 16 + r16) * 64 + cg];
            }
#pragma unroll
            for (int i = 0; i < 4; ++i)
#pragma unroll
                for (int j = 0; j < 4; ++j)
                    acc[i][j] = __builtin_amdgcn_mfma_f32_16x16x32_bf16(af[i], bff[j], acc[i][j], 0, 0, 0);
        }
        __syncthreads();
    }

    int rbase = (lane >> 4) * 4;
#pragma unroll
    for (int i = 0; i < 4; ++i) {
#pragma unroll
        for (int j = 0; j < 4; ++j) {
            int gr0 = by * 128 + wr * 64 + i * 16 + rbase;
            int gc  = bx * 128 + wc * 64 + j * 16 + (lane & 15);
            float bj = bias ? bias[gc] : 0.f;
#pragma unroll
            for (int r = 0; r < 4; ++r) {
                size_t idx = (size_t)(gr0 + r) * N + gc;
                float v = acc[i][j][r] + bj;
                if (MODE == 0)      ((u16*)out)[idx] = f2bf(v);
                else if (MODE == 1) ((u16*)out)[idx] = f2bf(gelu_f(v));
                else if (MODE == 2) ((float*)out)[idx] = resid[idx] + v;
                else                ((float*)out)[idx] = v;
            }
        }
    }
}

// ---------------------------------------------------------------------------
// LayerNorm: rows of 384 f32 -> 384 (bf16 or f32). block 256 = 4 waves,
// one row per wave. input row = row*inRowMul + inRowAdd, output row = row
// ---------------------------------------------------------------------------
template<bool BF16OUT>
__global__ __launch_bounds__(256) void ln_kernel(const float* __restrict__ x,
                                                 const float* __restrict__ w,
                                                 const float* __restrict__ b,
                                                 void* __restrict__ yout,
                                                 int inRowMul, int inRowAdd, int nRows) {
    int row = blockIdx.x * 4 + (threadIdx.x >> 6);
    if (row >= nRows) return;
    const float* xr = x + ((size_t)row * inRowMul + inRowAdd) * N_EMBD;
    int lane = threadIdx.x & 63;
    float v[6], s = 0.f, s2 = 0.f;
#pragma unroll
    for (int i = 0; i < 6; ++i) {
        v[i] = xr[lane + 64 * i];
        s += v[i]; s2 += v[i] * v[i];
    }
#pragma unroll
    for (int off = 32; off > 0; off >>= 1) {
        s  += __shfl_down(s, off);
        s2 += __shfl_down(s2, off);
    }
    float mean = __shfl(s, 0) * (1.f / 384.f);
    float var  = __shfl(s2, 0) * (1.f / 384.f) - mean * mean;
    float rs = rsqrtf(var + 1e-5f);
#pragma unroll
    for (int i = 0; i < 6; ++i) {
        int c = lane + 64 * i;
        float o = (v[i] - mean) * rs * w[c] + b[c];
        if (BF16OUT) ((u16*)yout)[(size_t)row * N_EMBD + c] = f2bf(o);
        else         ((float*)yout)[(size_t)row * N_EMBD + c] = o;
    }
}

// ---------------------------------------------------------------------------
// MFMA attention, v2 (REVERT, R15). One block (512 thr, 8 waves) per
// (head, batch). qkv bf16 [B*291, 1152] -> o bf16 [B*291, 384].
//
// R8-R14 post-mortem: three register-P variants (v4 monolithic, v5b 10+9,
// v6 5x4 chunks) ALL spill ~260 MB/dispatch scratch at the 128-VGPR cap,
// invariant to score-array size and load-window size — the fused
// QK->softmax->PV register chain at 512 threads is not allocatable under
// 128 VGPRs by this compiler, and the spill mechanism resists source-level
// control. Reverting to the v2 design: P round-trips through a per-wave
// LDS chunk buffer (wave-synchronous, no cross-wave barrier needed),
// VGPR=88, zero spill, measured 62.2-62.6 us twice (R1/R2).
// LDS 91,136 B -> 1 block/CU; occupancy 18.7% — known, accepted.
// ---------------------------------------------------------------------------
__global__ __launch_bounds__(512) void attn_mfma(const u16* __restrict__ qkv,
                                                 u16* __restrict__ o) {
    __shared__ __align__(16) u16 Ks[304 * 64];      // 38,912 B, swizzled
    __shared__ __align__(16) u16 Vt[64 * 328];      // 41,984 B
    __shared__ __align__(16) u16 Ps[8 * 16 * 40];   // 10,240 B (per-wave chunks)
    int h = blockIdx.x, b = blockIdx.y;
    int tid = threadIdx.x;
    int lane = tid & 63, wave = tid >> 6;
    int ln = lane & 15, quad = lane >> 4;
    int sw = ln & 7;
    const u16* base = qkv + (size_t)b * TT * 1152;

    // ---- stage K rows 0..290 (+clamped pad rows 291..303) via DMA ----
    // chunk c: LDS group (c&7) holds global col-group (c&7)^(row&7).
    for (int c = tid; c < 304 * 8; c += 512) {
        int row = c >> 3;
        int g   = (c & 7) ^ (row & 7);
        int srow = row < TT ? row : TT - 1;
        load16_lds(base + (size_t)srow * 1152 + 384 + h * 64 + g * 8, &Ks[c * 8]);
    }
    // ---- stage V transposed: Vt[d][key] ----
    for (int s = tid; s < TT * 8; s += 512) {
        int dg = s / TT, k = s - dg * TT;
        uint4 v = *(const uint4*)(base + (size_t)k * 1152 + 768 + h * 64 + dg * 8);
        const u16* pv = (const u16*)&v;
#pragma unroll
        for (int j = 0; j < 8; ++j) Vt[(dg * 8 + j) * 328 + k] = pv[j];
    }
    // zero pad cols 291..327 of Vt (disjoint from staged cols, no race)
    for (int s = tid; s < 64 * 37; s += 512) {
        int d = s / 37, c2 = s - d * 37;
        Vt[d * 328 + TT + c2] = 0;
    }
    __syncthreads();

    // ---- per-wave Q-tiles (19 tiles over 8 waves) ----
    for (int qt = wave; qt < 19; qt += 8) {
        int q0 = qt * 16;
        int qrow = q0 + ln; if (qrow > TT - 1) qrow = TT - 1;
        const u16* qp = base + (size_t)qrow * 1152 + h * 64;
        bf16x8 qf0 = *(const bf16x8*)(qp + quad * 8);
        bf16x8 qf1 = *(const bf16x8*)(qp + 32 + quad * 8);

        f32x4 sc[19];
#pragma unroll
        for (int kt = 0; kt < 19; ++kt) {
            const u16* kr = &Ks[(kt * 16 + ln) * 64];   // (row&7) == sw
            bf16x8 kb0 = *(const bf16x8*)&kr[(quad ^ sw) << 3];
            bf16x8 kb1 = *(const bf16x8*)&kr[((4 | quad) ^ sw) << 3];
            f32x4 z = {0.f, 0.f, 0.f, 0.f};
            z = __builtin_amdgcn_mfma_f32_16x16x32_bf16(qf0, kb0, z, 0, 0, 0);
            sc[kt] = __builtin_amdgcn_mfma_f32_16x16x32_bf16(qf1, kb1, z, 0, 0, 0);
        }

        // softmax on RAW scores; scale folded into the exp argument.
        const float C = 0.18033688011112042f;   // 0.125 * log2(e)
        float linv[4];
#pragma unroll
        for (int r = 0; r < 4; ++r) {
            float m = -1e30f;
            if (qt == 18) {
                // tile containing the readout row (q==290: attends only itself)
                int q = q0 + quad * 4 + r;
#pragma unroll
                for (int kt = 0; kt < 19; ++kt) {
                    int key = kt * 16 + ln;
                    bool ok = (key < TT) && (q != TT - 1 || key == TT - 1);
                    float s = ok ? sc[kt][r] : -1e30f;
                    sc[kt][r] = s;
                    m = fmaxf(m, s);
                }
            } else {
#pragma unroll
                for (int kt = 0; kt < 18; ++kt) m = fmaxf(m, sc[kt][r]);
                float s = (288 + ln < TT) ? sc[18][r] : -1e30f;  // keys 291..303
                sc[18][r] = s;
                m = fmaxf(m, s);
            }
            m = fmaxf(m, __shfl_xor(m, 1));
            m = fmaxf(m, __shfl_xor(m, 2));
            m = fmaxf(m, __shfl_xor(m, 4));
            m = fmaxf(m, __shfl_xor(m, 8));
            float mc = m * C;
            float l = 0.f;
#pragma unroll
            for (int kt = 0; kt < 19; ++kt) {
                float p = __builtin_amdgcn_exp2f(fmaf(sc[kt][r], C, -mc));
                sc[kt][r] = p;
                l += p;
            }
            l += __shfl_xor(l, 1);
            l += __shfl_xor(l, 2);
            l += __shfl_xor(l, 4);
            l += __shfl_xor(l, 8);
            linv[r] = 1.f / l;
        }

        // ---- PV: write one 32-key P chunk, consume it, repeat (wave-sync) ----
        u16* Pw = &Ps[wave * 16 * 40];
        f32x4 of[4];
#pragma unroll
        for (int nt = 0; nt < 4; ++nt)
#pragma unroll
            for (int r = 0; r < 4; ++r) of[nt][r] = 0.f;
#pragma unroll
        for (int kt2 = 0; kt2 < 10; ++kt2) {
#pragma unroll
            for (int half = 0; half < 2; ++half) {
                int kt = kt2 * 2 + half;
#pragma unroll
                for (int r = 0; r < 4; ++r) {
                    float v = (kt < 19) ? sc[kt][r] : 0.f;   // kt==19: zero pad
                    Pw[(quad * 4 + r) * 40 + half * 16 + ln] = f2bf(v);
                }
            }
            bf16x8 pa = *(const bf16x8*)&Pw[ln * 40 + quad * 8];
#pragma unroll
            for (int nt = 0; nt < 4; ++nt) {
                bf16x8 vb = *(const bf16x8*)&Vt[(nt * 16 + ln) * 328 + kt2 * 32 + quad * 8];
                of[nt] = __builtin_amdgcn_mfma_f32_16x16x32_bf16(pa, vb, of[nt], 0, 0, 0);
            }
        }

#pragma unroll
        for (int nt = 0; nt < 4; ++nt) {
#pragma unroll
            for (int r = 0; r < 4; ++r) {
                int q = q0 + quad * 4 + r;
                if (q < TT)
                    o[((size_t)(b * TT + q)) * N_EMBD + h * 64 + nt * 16 + ln] =
                        f2bf(of[nt][r] * linv[r]);
            }
        }
    }
}

// ---------------------------------------------------------------------------
// Tokenizer helpers
// ---------------------------------------------------------------------------
__global__ __launch_bounds__(256) void patchify_kernel(const float* __restrict__ images,
                                                       u16* __restrict__ P) {
    int idx = blockIdx.x * 256 + threadIdx.x;  // 36864*192 exact
    int col = idx % 192, row = idx / 192;
    int p = row % 144, bt = row / 144;
    int c = col % 3, pp = col / 3;
    int pw = pp & 7, ph = pp >> 3;
    int hp = p / 12, wp = p % 12;
    float v = images[(((size_t)bt * 3 + c) * 96 + hp * 8 + ph) * 96 + wp * 8 + pw];
    P[idx] = f2bf(v);
}

__global__ __launch_bounds__(256) void img_scatter_kernel(const float* __restrict__ imgtok,
                                                          const float* __restrict__ temb,
                                                          const float* __restrict__ pos,
                                                          float* __restrict__ xw) {
    int idx = blockIdx.x * 256 + threadIdx.x;  // 36864*384 exact
    int n = idx % 384, row = idx / 384;
    int p = row % 144, bt = row / 144;
    int t = bt & 1, b = bt >> 1;
    int tok = t * 145 + 1 + p;
    xw[((size_t)b * TT + tok) * N_EMBD + n] =
        imgtok[idx] + temb[t * N_EMBD + n] + pos[(size_t)tok * N_EMBD + n];
}

__global__ __launch_bounds__(384) void st_kernel(const float* __restrict__ state,
                                                 const float* __restrict__ w1,
                                                 const float* __restrict__ b1,
                                                 const float* __restrict__ w2,
                                                 const float* __restrict__ b2,
                                                 const float* __restrict__ temb,
                                                 const float* __restrict__ pos,
                                                 float* __restrict__ xw) {
    int bt = blockIdx.x;
    int t = bt & 1, b = bt >> 1;
    int n = threadIdx.x;
    float s0 = state[bt * 2], s1 = state[bt * 2 + 1];
    float acc = b2[n];
#pragma unroll
    for (int j = 0; j < 32; ++j) {
        float hh = fmaxf(s0 * w1[j] + s1 * w1[32 + j] + b1[j], 0.f);
        acc += hh * w2[j * N_EMBD + n];
    }
    int tok = t * 145;
    xw[((size_t)b * TT + tok) * N_EMBD + n] =
        acc + temb[t * N_EMBD + n] + pos[(size_t)tok * N_EMBD + n];
}

__global__ __launch_bounds__(256) void ro_kernel(const float* __restrict__ readout,
                                                 const float* __restrict__ pos,
                                                 float* __restrict__ xw) {
    int idx = blockIdx.x * 256 + threadIdx.x;  // 128*384 exact
    int n = idx % 384, b = idx / 384;
    xw[((size_t)b * TT + 290) * N_EMBD + n] = readout[n] + pos[(size_t)290 * N_EMBD + n];
}

// ---------------------------------------------------------------------------
// Workspace layout (all offsets 256B-aligned). TOTAL = 175,325,184 B (~167 MB)
// ---------------------------------------------------------------------------
extern "C" void kernel_launch(void* const* d_in, const int* in_sizes, int n_in,
                              void* d_out, int out_size, void* d_ws, size_t ws_size,
                              hipStream_t stream) {
    const float* images   = (const float*)d_in[0];
    const float* state    = (const float*)d_in[1];
    const float* img_w    = (const float*)d_in[2];
    const float* img_b    = (const float*)d_in[3];
    const float* img_temb = (const float*)d_in[4];
    const float* st_w1    = (const float*)d_in[5];
    const float* st_b1    = (const float*)d_in[6];
    const float* st_w2    = (const float*)d_in[7];
    const float* st_b2    = (const float*)d_in[8];
    const float* st_temb  = (const float*)d_in[9];
    const float* readout  = (const float*)d_in[10];
    const float* pos      = (const float*)d_in[11];
    const float* ln1_w    = (const float*)d_in[12];
    const float* ln1_b    = (const float*)d_in[13];
    const float* attn_w   = (const float*)d_in[14];
    const float* attn_b   = (const float*)d_in[15];
    const float* proj_w   = (const float*)d_in[16];
    const float* proj_b   = (const float*)d_in[17];
    const float* ln2_w    = (const float*)d_in[18];
    const float* ln2_b    = (const float*)d_in[19];
    const float* fc_w     = (const float*)d_in[20];
    const float* fc_b     = (const float*)d_in[21];
    const float* fc2_w    = (const float*)d_in[22];
    const float* fc2_b    = (const float*)d_in[23];
    const float* lnf_w    = (const float*)d_in[24];
    const float* lnf_b    = (const float*)d_in[25];

    char* ws = (char*)d_ws;
    float* XW   = (float*)(ws);
    u16*   Y    = (u16*)(ws + 57212928ull);       // also O (attn output)
    u16*   SH   = (u16*)(ws + 85819392ull);       // QKV | G | setup
    u16*   QKV  = SH;
    u16*   G    = SH;
    u16*   P    = SH;                              // setup: patches [36864,192]
    float* IMGT = (float*)(ws + 85819392ull + 14155776ull);  // setup: [36864,384] f32
    u16*   WQKVl  = (u16*)(ws + 171638784ull);    // [1152][384]
    u16*   WPROJl = (u16*)(ws + 172523520ull);    // [384][384]
    u16*   WFCl   = (u16*)(ws + 172818432ull);    // [1536][384]
    u16*   WFC2Tl = (u16*)(ws + 173998080ull);    // [384][1536]
    u16*   WIMG   = (u16*)(ws + 175177728ull);    // [384][192]

    // ---- tokenizers -> XW [128*291, 384] f32 ----
    transpose_cvt<<<dim3(12, 6), 256, 0, stream>>>(img_w, WIMG, 192, 384);
    patchify_kernel<<<27648, 256, 0, stream>>>(images, P);
    gemm_bt<3><<<dim3(3, 288), 256, 0, stream>>>(P, WIMG, 192, img_b, IMGT, nullptr, 384, 192);
    img_scatter_kernel<<<55296, 256, 0, stream>>>(IMGT, img_temb, pos, XW);
    st_kernel<<<256, 384, 0, stream>>>(state, st_w1, st_b1, st_w2, st_b2, st_temb, pos, XW);
    ro_kernel<<<192, 256, 0, stream>>>(readout, pos, XW);

    // ---- transformer layers (M = 37248 = 128*291) ----
    // MLP is M-split (146 + 145 row-blocks): full-width G half fits the QKV
    // region and fc2 runs as ONE K=1536 GEMM per half (halves f32 resid traffic).
    const size_t M0 = 18688;   // 146 * 128
    for (int l = 0; l < 12; ++l) {
        transpose_layer<<<1728, 256, 0, stream>>>(attn_w, proj_w, fc_w, fc2_w,
                                                  WQKVl, WPROJl, WFCl, WFC2Tl, l);
        ln_kernel<true><<<9312, 256, 0, stream>>>(XW, ln1_w + l * 384, ln1_b + l * 384, Y, 1, 0, 37248);
        gemm_bt<0><<<dim3(9, 291), 256, 0, stream>>>(Y, WQKVl, 384, attn_b + l * 1152,
                                                     QKV, nullptr, 1152, 384);
        attn_mfma<<<dim3(6, 128), 512, 0, stream>>>(QKV, Y);   // O aliases Y
        gemm_bt<2><<<dim3(3, 291), 256, 0, stream>>>(Y, WPROJl, 384, proj_b + l * 384,
                                                     XW, XW, 384, 384);
        ln_kernel<true><<<9312, 256, 0, stream>>>(XW, ln2_w + l * 384, ln2_b + l * 384, Y, 1, 0, 37248);
        // MLP half 0: rows [0, 18688)
        gemm_bt<1><<<dim3(12, 146), 256, 0, stream>>>(Y, WFCl, 384, fc_b + l * 1536,
                                                      G, nullptr, 1536, 384);
        gemm_bt<2><<<dim3(3, 146), 256, 0, stream>>>(G, WFC2Tl, 1536, fc2_b + l * 384,
                                                     XW, XW, 384, 1536);
        // MLP half 1: rows [18688, 37248)
        gemm_bt<1><<<dim3(12, 145), 256, 0, stream>>>(Y + M0 * 384, WFCl, 384, fc_b + l * 1536,
                                                      G, nullptr, 1536, 384);
        gemm_bt<2><<<dim3(3, 145), 256, 0, stream>>>(G, WFC2Tl, 1536, fc2_b + l * 384,
                                                     XW + M0 * 384, XW + M0 * 384, 384, 1536);
    }
    // final LN on readout rows -> d_out [128, 384] f32
    ln_kernel<false><<<32, 256, 0, stream>>>(XW, lnf_w, lnf_b, d_out, TT, 290, 128);
}

// Round 10
// 4324.300 us; speedup vs baseline: 1.3853x; 1.0136x over previous
//
#include <hip/hip_runtime.h>

typedef unsigned short u16;
typedef unsigned int u32;

typedef __bf16 bf16x8 __attribute__((ext_vector_type(8)));
typedef float  f32x4  __attribute__((ext_vector_type(4)));

#define N_EMBD 384
#define TT     291
#define NB     128

__device__ __forceinline__ u16 f2bf(float x) {
    union { float f; u32 u; } v; v.f = x;
    u32 r = v.u + 0x7FFFu + ((v.u >> 16) & 1u);
    return (u16)(r >> 16);
}
__device__ __forceinline__ float bfl(u32 u) { return __uint_as_float(u << 16); }
__device__ __forceinline__ float bfh(u32 u) { return __uint_as_float(u & 0xFFFF0000u); }

__device__ __forceinline__ float gelu_f(float x) {
    float u = 0.7978845608028654f * x * (1.f + 0.044715f * x * x);
    float e = __expf(2.f * u);
    float t = 1.f - 2.f / (e + 1.f);   // tanh(u), safe at +-inf
    return 0.5f * x * (1.f + t);
}

// async global->LDS DMA, 16B per lane. LDS dest must be wave-uniform base +
// lane*16 in lane order (m104/m108) — caller guarantees the mapping.
__device__ __forceinline__ void load16_lds(const u16* g, u16* l) {
    __builtin_amdgcn_global_load_lds(
        (const __attribute__((address_space(1))) u32*)g,
        (__attribute__((address_space(3))) u32*)l, 16, 0, 0);
}

// ---------------------------------------------------------------------------
// 32x32 transpose+convert tile body: out[c0+rr][r0+cc] = in[r0+cc][c0+rr]
// ---------------------------------------------------------------------------
__device__ __forceinline__ void tr_tile(const float* __restrict__ src,
                                        u16* __restrict__ dst,
                                        int R, int C, int r0, int c0, int tid) {
    __shared__ float tile[32][33];
    int cc = tid & 31, rr0 = tid >> 5;
#pragma unroll
    for (int s = 0; s < 4; ++s) {
        int rr = rr0 + s * 8;
        tile[rr][cc] = src[(size_t)(r0 + rr) * C + c0 + cc];
    }
    __syncthreads();
#pragma unroll
    for (int s = 0; s < 4; ++s) {
        int rr = rr0 + s * 8;
        dst[(size_t)(c0 + rr) * R + (r0 + cc)] = f2bf(tile[cc][rr]);
    }
}

// generic: in[R][C] f32 -> out[C][R] bf16, grid (C/32, R/32)
__global__ __launch_bounds__(256) void transpose_cvt(const float* __restrict__ in,
                                                     u16* __restrict__ out, int R, int C) {
    tr_tile(in, out, R, C, blockIdx.y * 32, blockIdx.x * 32, threadIdx.x);
}

// fused per-layer weight transpose: all 4 matrices of layer l, grid 1728
__global__ __launch_bounds__(256) void transpose_layer(const float* __restrict__ attn_w,
                                                       const float* __restrict__ proj_w,
                                                       const float* __restrict__ fc_w,
                                                       const float* __restrict__ fc2_w,
                                                       u16* __restrict__ wqkv,
                                                       u16* __restrict__ wproj,
                                                       u16* __restrict__ wfc,
                                                       u16* __restrict__ wfc2t,
                                                       int l) {
    int t = blockIdx.x;
    const float* src; u16* dst; int R, C, tx, ty;
    if (t < 432)       { int i = t;        src = attn_w + (size_t)l * 384 * 1152; dst = wqkv;  R = 384;  C = 1152; tx = i % 36; ty = i / 36; }
    else if (t < 576)  { int i = t - 432;  src = proj_w + (size_t)l * 384 * 384;  dst = wproj; R = 384;  C = 384;  tx = i % 12; ty = i / 12; }
    else if (t < 1152) { int i = t - 576;  src = fc_w   + (size_t)l * 384 * 1536; dst = wfc;   R = 384;  C = 1536; tx = i % 48; ty = i / 48; }
    else               { int i = t - 1152; src = fc2_w  + (size_t)l * 1536 * 384; dst = wfc2t; R = 1536; C = 384;  tx = i % 12; ty = i / 12; }
    tr_tile(src, dst, R, C, ty * 32, tx * 32, threadIdx.x);
}

// ---------------------------------------------------------------------------
// bf16 MFMA GEMM:  C[M,N] = A[M,K] @ B[K,N]
// A row-major bf16 (row stride K), BT row-major bf16 [N][ldb] (B^T slice).
// Tile 128x128, BK=64, 256 threads (4 waves = 2x2 of 64x64, each 4x4 MFMA).
// LDS: unpadded [128][64] via global_load_lds, 3-bit XOR col-group swizzle.
// XCD-chunked bijective blockIdx swizzle (T1/m204) for A-panel L2 locality.
// K must be a multiple of 64.
// MODE 0: out bf16 = acc+bias        MODE 1: out bf16 = gelu(acc+bias)
// MODE 2: out bf16 = resid(bf16)+acc+bias   (R16: residual stream is bf16)
// MODE 3: out f32  = acc+bias
// out row stride = N. grid (N/128, ceil(M/128))
// ---------------------------------------------------------------------------
template<int MODE>
__global__ __launch_bounds__(256) void gemm_bt(const u16* __restrict__ A,
                                               const u16* __restrict__ BT, int ldb,
                                               const float* __restrict__ bias,
                                               void* __restrict__ out,
                                               const u16* __restrict__ resid,
                                               int N, int K) {
    __shared__ u16 As[128 * 64];   // 16 KB
    __shared__ u16 Bs[128 * 64];   // 16 KB
    int tid = threadIdx.x;
    int lane = tid & 63, wave = tid >> 6;
    int wr = wave >> 1, wc = wave & 1;

    // ---- XCD-chunked bijective block swizzle (m204) ----
    int nwg  = gridDim.x * gridDim.y;
    int orig = blockIdx.y * gridDim.x + blockIdx.x;
    int qq = nwg >> 3, rr = nwg & 7;
    int xcd = orig & 7, idx0 = orig >> 3;
    int wg = (xcd < rr ? xcd * (qq + 1) : rr * (qq + 1) + (xcd - rr) * qq) + idx0;
    int bx = wg % gridDim.x, by = wg / gridDim.x;

    const u16* Ab = A  + (size_t)by * 128 * K;
    const u16* Bb = BT + (size_t)bx * 128 * ldb;

    f32x4 acc[4][4];
#pragma unroll
    for (int i = 0; i < 4; ++i)
#pragma unroll
        for (int j = 0; j < 4; ++j)
#pragma unroll
            for (int r = 0; r < 4; ++r) acc[i][j][r] = 0.f;

    int r16  = lane & 15;
    int quad = lane >> 4;
    int sw   = r16 & 7;

    // staging map: seg in [0,1024), 16B each; row = seg>>3, LDS slot cg = seg&7
    // holds global col-group (seg&7) ^ (row&7).
    int srow[4], scol[4];
#pragma unroll
    for (int s = 0; s < 4; ++s) {
        int seg = s * 256 + tid;
        srow[s] = seg >> 3;
        scol[s] = (((seg & 7) ^ (srow[s] & 7)) << 3);
    }

    for (int kt = 0; kt < K; kt += 64) {
#pragma unroll
        for (int s = 0; s < 4; ++s) {
            int seg = s * 256 + tid;
            load16_lds(Ab + (size_t)srow[s] * K   + kt + scol[s], &As[seg * 8]);
            load16_lds(Bb + (size_t)srow[s] * ldb + kt + scol[s], &Bs[seg * 8]);
        }
        __syncthreads();
#pragma unroll
        for (int kk = 0; kk < 2; ++kk) {     // k-offsets 0, 32 within the 64-slice
            bf16x8 af[4], bff[4];
#pragma unroll
            for (int i = 0; i < 4; ++i) {
                int cg = ((kk * 4 + quad) ^ sw) << 3;
                af[i]  = *(const bf16x8*)&As[(wr * 64 + i * 16 + r16) * 64 + cg];
                bff[i] = *(const bf16x8*)&Bs[(wc * 64 + i * 16 + r16) * 64 + cg];
            }
#pragma unroll
            for (int i = 0; i < 4; ++i)
#pragma unroll
                for (int j = 0; j < 4; ++j)
                    acc[i][j] = __builtin_amdgcn_mfma_f32_16x16x32_bf16(af[i], bff[j], acc[i][j], 0, 0, 0);
        }
        __syncthreads();
    }

    int rbase = (lane >> 4) * 4;
#pragma unroll
    for (int i = 0; i < 4; ++i) {
#pragma unroll
        for (int j = 0; j < 4; ++j) {
            int gr0 = by * 128 + wr * 64 + i * 16 + rbase;
            int gc  = bx * 128 + wc * 64 + j * 16 + (lane & 15);
            float bj = bias ? bias[gc] : 0.f;
#pragma unroll
            for (int r = 0; r < 4; ++r) {
                size_t idx = (size_t)(gr0 + r) * N + gc;
                float v = acc[i][j][r] + bj;
                if (MODE == 0)      ((u16*)out)[idx] = f2bf(v);
                else if (MODE == 1) ((u16*)out)[idx] = f2bf(gelu_f(v));
                else if (MODE == 2) {
                    float rv = bfl((u32)resid[idx]);
                    ((u16*)out)[idx] = f2bf(rv + v);
                }
                else                ((float*)out)[idx] = v;
            }
        }
    }
}

// ---------------------------------------------------------------------------
// LayerNorm (R16: bf16 input): rows of 384 bf16 -> 384 (bf16 or f32).
// block 256 = 4 waves, one row per wave. Vectorized u32 (bf16x2) loads;
// bf16 output packed as u32 pairs (G13 — never scalar bf16 loads).
// input row = row*inRowMul + inRowAdd, output row = row.
// ---------------------------------------------------------------------------
template<bool BF16OUT>
__global__ __launch_bounds__(256) void ln_kernel(const u16* __restrict__ x,
                                                 const float* __restrict__ w,
                                                 const float* __restrict__ b,
                                                 void* __restrict__ yout,
                                                 int inRowMul, int inRowAdd, int nRows) {
    int row = blockIdx.x * 4 + (threadIdx.x >> 6);
    if (row >= nRows) return;
    const u32* xr = (const u32*)(x + ((size_t)row * inRowMul + inRowAdd) * N_EMBD);
    int lane = threadIdx.x & 63;
    float vl[3], vh[3], s = 0.f, s2 = 0.f;
#pragma unroll
    for (int j = 0; j < 3; ++j) {
        u32 u = xr[lane + 64 * j];
        float lo = bfl(u), hi = bfh(u);
        vl[j] = lo; vh[j] = hi;
        s += lo + hi; s2 += lo * lo + hi * hi;
    }
#pragma unroll
    for (int off = 32; off > 0; off >>= 1) {
        s  += __shfl_down(s, off);
        s2 += __shfl_down(s2, off);
    }
    float mean = __shfl(s, 0) * (1.f / 384.f);
    float var  = __shfl(s2, 0) * (1.f / 384.f) - mean * mean;
    float rs = rsqrtf(var + 1e-5f);
#pragma unroll
    for (int j = 0; j < 3; ++j) {
        int c = 2 * (lane + 64 * j);
        float ol = (vl[j] - mean) * rs * w[c]     + b[c];
        float oh = (vh[j] - mean) * rs * w[c + 1] + b[c + 1];
        if (BF16OUT) {
            u32 pk = (u32)f2bf(ol) | ((u32)f2bf(oh) << 16);
            ((u32*)yout)[(size_t)row * 192 + lane + 64 * j] = pk;
        } else {
            ((float*)yout)[(size_t)row * N_EMBD + c]     = ol;
            ((float*)yout)[(size_t)row * N_EMBD + c + 1] = oh;
        }
    }
}

// ---------------------------------------------------------------------------
// MFMA attention, v2 (verified, R15). One block (512 thr, 8 waves) per
// (head, batch). qkv bf16 [B*291, 1152] -> o bf16 [B*291, 384].
// VGPR=88, zero spill, 62.4 us measured (R1/R2/R9).
// ---------------------------------------------------------------------------
__global__ __launch_bounds__(512) void attn_mfma(const u16* __restrict__ qkv,
                                                 u16* __restrict__ o) {
    __shared__ __align__(16) u16 Ks[304 * 64];      // 38,912 B, swizzled
    __shared__ __align__(16) u16 Vt[64 * 328];      // 41,984 B
    __shared__ __align__(16) u16 Ps[8 * 16 * 40];   // 10,240 B (per-wave chunks)
    int h = blockIdx.x, b = blockIdx.y;
    int tid = threadIdx.x;
    int lane = tid & 63, wave = tid >> 6;
    int ln = lane & 15, quad = lane >> 4;
    int sw = ln & 7;
    const u16* base = qkv + (size_t)b * TT * 1152;

    // ---- stage K rows 0..290 (+clamped pad rows 291..303) via DMA ----
    // chunk c: LDS group (c&7) holds global col-group (c&7)^(row&7).
    for (int c = tid; c < 304 * 8; c += 512) {
        int row = c >> 3;
        int g   = (c & 7) ^ (row & 7);
        int srow = row < TT ? row : TT - 1;
        load16_lds(base + (size_t)srow * 1152 + 384 + h * 64 + g * 8, &Ks[c * 8]);
    }
    // ---- stage V transposed: Vt[d][key] ----
    for (int s = tid; s < TT * 8; s += 512) {
        int dg = s / TT, k = s - dg * TT;
        uint4 v = *(const uint4*)(base + (size_t)k * 1152 + 768 + h * 64 + dg * 8);
        const u16* pv = (const u16*)&v;
#pragma unroll
        for (int j = 0; j < 8; ++j) Vt[(dg * 8 + j) * 328 + k] = pv[j];
    }
    // zero pad cols 291..327 of Vt (disjoint from staged cols, no race)
    for (int s = tid; s < 64 * 37; s += 512) {
        int d = s / 37, c2 = s - d * 37;
        Vt[d * 328 + TT + c2] = 0;
    }
    __syncthreads();

    // ---- per-wave Q-tiles (19 tiles over 8 waves) ----
    for (int qt = wave; qt < 19; qt += 8) {
        int q0 = qt * 16;
        int qrow = q0 + ln; if (qrow > TT - 1) qrow = TT - 1;
        const u16* qp = base + (size_t)qrow * 1152 + h * 64;
        bf16x8 qf0 = *(const bf16x8*)(qp + quad * 8);
        bf16x8 qf1 = *(const bf16x8*)(qp + 32 + quad * 8);

        f32x4 sc[19];
#pragma unroll
        for (int kt = 0; kt < 19; ++kt) {
            const u16* kr = &Ks[(kt * 16 + ln) * 64];   // (row&7) == sw
            bf16x8 kb0 = *(const bf16x8*)&kr[(quad ^ sw) << 3];
            bf16x8 kb1 = *(const bf16x8*)&kr[((4 | quad) ^ sw) << 3];
            f32x4 z = {0.f, 0.f, 0.f, 0.f};
            z = __builtin_amdgcn_mfma_f32_16x16x32_bf16(qf0, kb0, z, 0, 0, 0);
            sc[kt] = __builtin_amdgcn_mfma_f32_16x16x32_bf16(qf1, kb1, z, 0, 0, 0);
        }

        // softmax on RAW scores; scale folded into the exp argument.
        const float C = 0.18033688011112042f;   // 0.125 * log2(e)
        float linv[4];
#pragma unroll
        for (int r = 0; r < 4; ++r) {
            float m = -1e30f;
            if (qt == 18) {
                // tile containing the readout row (q==290: attends only itself)
                int q = q0 + quad * 4 + r;
#pragma unroll
                for (int kt = 0; kt < 19; ++kt) {
                    int key = kt * 16 + ln;
                    bool ok = (key < TT) && (q != TT - 1 || key == TT - 1);
                    float s = ok ? sc[kt][r] : -1e30f;
                    sc[kt][r] = s;
                    m = fmaxf(m, s);
                }
            } else {
#pragma unroll
                for (int kt = 0; kt < 18; ++kt) m = fmaxf(m, sc[kt][r]);
                float s = (288 + ln < TT) ? sc[18][r] : -1e30f;  // keys 291..303
                sc[18][r] = s;
                m = fmaxf(m, s);
            }
            m = fmaxf(m, __shfl_xor(m, 1));
            m = fmaxf(m, __shfl_xor(m, 2));
            m = fmaxf(m, __shfl_xor(m, 4));
            m = fmaxf(m, __shfl_xor(m, 8));
            float mc = m * C;
            float l = 0.f;
#pragma unroll
            for (int kt = 0; kt < 19; ++kt) {
                float p = __builtin_amdgcn_exp2f(fmaf(sc[kt][r], C, -mc));
                sc[kt][r] = p;
                l += p;
            }
            l += __shfl_xor(l, 1);
            l += __shfl_xor(l, 2);
            l += __shfl_xor(l, 4);
            l += __shfl_xor(l, 8);
            linv[r] = 1.f / l;
        }

        // ---- PV: write one 32-key P chunk, consume it, repeat (wave-sync) ----
        u16* Pw = &Ps[wave * 16 * 40];
        f32x4 of[4];
#pragma unroll
        for (int nt = 0; nt < 4; ++nt)
#pragma unroll
            for (int r = 0; r < 4; ++r) of[nt][r] = 0.f;
#pragma unroll
        for (int kt2 = 0; kt2 < 10; ++kt2) {
#pragma unroll
            for (int half = 0; half < 2; ++half) {
                int kt = kt2 * 2 + half;
#pragma unroll
                for (int r = 0; r < 4; ++r) {
                    float v = (kt < 19) ? sc[kt][r] : 0.f;   // kt==19: zero pad
                    Pw[(quad * 4 + r) * 40 + half * 16 + ln] = f2bf(v);
                }
            }
            bf16x8 pa = *(const bf16x8*)&Pw[ln * 40 + quad * 8];
#pragma unroll
            for (int nt = 0; nt < 4; ++nt) {
                bf16x8 vb = *(const bf16x8*)&Vt[(nt * 16 + ln) * 328 + kt2 * 32 + quad * 8];
                of[nt] = __builtin_amdgcn_mfma_f32_16x16x32_bf16(pa, vb, of[nt], 0, 0, 0);
            }
        }

#pragma unroll
        for (int nt = 0; nt < 4; ++nt) {
#pragma unroll
            for (int r = 0; r < 4; ++r) {
                int q = q0 + quad * 4 + r;
                if (q < TT)
                    o[((size_t)(b * TT + q)) * N_EMBD + h * 64 + nt * 16 + ln] =
                        f2bf(of[nt][r] * linv[r]);
            }
        }
    }
}

// ---------------------------------------------------------------------------
// Tokenizer helpers (R16: XW is bf16)
// ---------------------------------------------------------------------------
__global__ __launch_bounds__(256) void patchify_kernel(const float* __restrict__ images,
                                                       u16* __restrict__ P) {
    int idx = blockIdx.x * 256 + threadIdx.x;  // 36864*192 exact
    int col = idx % 192, row = idx / 192;
    int p = row % 144, bt = row / 144;
    int c = col % 3, pp = col / 3;
    int pw = pp & 7, ph = pp >> 3;
    int hp = p / 12, wp = p % 12;
    float v = images[(((size_t)bt * 3 + c) * 96 + hp * 8 + ph) * 96 + wp * 8 + pw];
    P[idx] = f2bf(v);
}

__global__ __launch_bounds__(256) void img_scatter_kernel(const float* __restrict__ imgtok,
                                                          const float* __restrict__ temb,
                                                          const float* __restrict__ pos,
                                                          u16* __restrict__ xw) {
    int idx = blockIdx.x * 256 + threadIdx.x;  // 36864*384 exact
    int n = idx % 384, row = idx / 384;
    int p = row % 144, bt = row / 144;
    int t = bt & 1, b = bt >> 1;
    int tok = t * 145 + 1 + p;
    xw[((size_t)b * TT + tok) * N_EMBD + n] =
        f2bf(imgtok[idx] + temb[t * N_EMBD + n] + pos[(size_t)tok * N_EMBD + n]);
}

__global__ __launch_bounds__(384) void st_kernel(const float* __restrict__ state,
                                                 const float* __restrict__ w1,
                                                 const float* __restrict__ b1,
                                                 const float* __restrict__ w2,
                                                 const float* __restrict__ b2,
                                                 const float* __restrict__ temb,
                                                 const float* __restrict__ pos,
                                                 u16* __restrict__ xw) {
    int bt = blockIdx.x;
    int t = bt & 1, b = bt >> 1;
    int n = threadIdx.x;
    float s0 = state[bt * 2], s1 = state[bt * 2 + 1];
    float acc = b2[n];
#pragma unroll
    for (int j = 0; j < 32; ++j) {
        float hh = fmaxf(s0 * w1[j] + s1 * w1[32 + j] + b1[j], 0.f);
        acc += hh * w2[j * N_EMBD + n];
    }
    int tok = t * 145;
    xw[((size_t)b * TT + tok) * N_EMBD + n] =
        f2bf(acc + temb[t * N_EMBD + n] + pos[(size_t)tok * N_EMBD + n]);
}

__global__ __launch_bounds__(256) void ro_kernel(const float* __restrict__ readout,
                                                 const float* __restrict__ pos,
                                                 u16* __restrict__ xw) {
    int idx = blockIdx.x * 256 + threadIdx.x;  // 128*384 exact
    int n = idx % 384, b = idx / 384;
    xw[((size_t)b * TT + 290) * N_EMBD + n] = f2bf(readout[n] + pos[(size_t)290 * N_EMBD + n]);
}

// ---------------------------------------------------------------------------
// Workspace layout (all offsets 256B-aligned, unchanged from R9; XW region
// now holds bf16 [37248,384] = 28.6 MB, rest of the old slot unused).
// ---------------------------------------------------------------------------
extern "C" void kernel_launch(void* const* d_in, const int* in_sizes, int n_in,
                              void* d_out, int out_size, void* d_ws, size_t ws_size,
                              hipStream_t stream) {
    const float* images   = (const float*)d_in[0];
    const float* state    = (const float*)d_in[1];
    const float* img_w    = (const float*)d_in[2];
    const float* img_b    = (const float*)d_in[3];
    const float* img_temb = (const float*)d_in[4];
    const float* st_w1    = (const float*)d_in[5];
    const float* st_b1    = (const float*)d_in[6];
    const float* st_w2    = (const float*)d_in[7];
    const float* st_b2    = (const float*)d_in[8];
    const float* st_temb  = (const float*)d_in[9];
    const float* readout  = (const float*)d_in[10];
    const float* pos      = (const float*)d_in[11];
    const float* ln1_w    = (const float*)d_in[12];
    const float* ln1_b    = (const float*)d_in[13];
    const float* attn_w   = (const float*)d_in[14];
    const float* attn_b   = (const float*)d_in[15];
    const float* proj_w   = (const float*)d_in[16];
    const float* proj_b   = (const float*)d_in[17];
    const float* ln2_w    = (const float*)d_in[18];
    const float* ln2_b    = (const float*)d_in[19];
    const float* fc_w     = (const float*)d_in[20];
    const float* fc_b     = (const float*)d_in[21];
    const float* fc2_w    = (const float*)d_in[22];
    const float* fc2_b    = (const float*)d_in[23];
    const float* lnf_w    = (const float*)d_in[24];
    const float* lnf_b    = (const float*)d_in[25];

    char* ws = (char*)d_ws;
    u16*   XW   = (u16*)(ws);                      // bf16 residual stream (R16)
    u16*   Y    = (u16*)(ws + 57212928ull);       // also O (attn output)
    u16*   SH   = (u16*)(ws + 85819392ull);       // QKV | G | setup
    u16*   QKV  = SH;
    u16*   G    = SH;
    u16*   P    = SH;                              // setup: patches [36864,192]
    float* IMGT = (float*)(ws + 85819392ull + 14155776ull);  // setup: [36864,384] f32
    u16*   WQKVl  = (u16*)(ws + 171638784ull);    // [1152][384]
    u16*   WPROJl = (u16*)(ws + 172523520ull);    // [384][384]
    u16*   WFCl   = (u16*)(ws + 172818432ull);    // [1536][384]
    u16*   WFC2Tl = (u16*)(ws + 173998080ull);    // [384][1536]
    u16*   WIMG   = (u16*)(ws + 175177728ull);    // [384][192]

    // ---- tokenizers -> XW [128*291, 384] bf16 ----
    transpose_cvt<<<dim3(12, 6), 256, 0, stream>>>(img_w, WIMG, 192, 384);
    patchify_kernel<<<27648, 256, 0, stream>>>(images, P);
    gemm_bt<3><<<dim3(3, 288), 256, 0, stream>>>(P, WIMG, 192, img_b, IMGT, nullptr, 384, 192);
    img_scatter_kernel<<<55296, 256, 0, stream>>>(IMGT, img_temb, pos, XW);
    st_kernel<<<256, 384, 0, stream>>>(state, st_w1, st_b1, st_w2, st_b2, st_temb, pos, XW);
    ro_kernel<<<192, 256, 0, stream>>>(readout, pos, XW);

    // ---- transformer layers (M = 37248 = 128*291) ----
    // Residual stream XW is bf16: residual adds happen in f32 inside the
    // gemm epilogue (acc + bf16-resid), rounded once per junction.
    // MLP is M-split (146 + 145 row-blocks): full-width G half fits the QKV
    // region and fc2 runs as ONE K=1536 GEMM per half.
    const size_t M0 = 18688;   // 146 * 128
    for (int l = 0; l < 12; ++l) {
        transpose_layer<<<1728, 256, 0, stream>>>(attn_w, proj_w, fc_w, fc2_w,
                                                  WQKVl, WPROJl, WFCl, WFC2Tl, l);
        ln_kernel<true><<<9312, 256, 0, stream>>>(XW, ln1_w + l * 384, ln1_b + l * 384, Y, 1, 0, 37248);
        gemm_bt<0><<<dim3(9, 291), 256, 0, stream>>>(Y, WQKVl, 384, attn_b + l * 1152,
                                                     QKV, nullptr, 1152, 384);
        attn_mfma<<<dim3(6, 128), 512, 0, stream>>>(QKV, Y);   // O aliases Y
        gemm_bt<2><<<dim3(3, 291), 256, 0, stream>>>(Y, WPROJl, 384, proj_b + l * 384,
                                                     XW, XW, 384, 384);
        ln_kernel<true><<<9312, 256, 0, stream>>>(XW, ln2_w + l * 384, ln2_b + l * 384, Y, 1, 0, 37248);
        // MLP half 0: rows [0, 18688)
        gemm_bt<1><<<dim3(12, 146), 256, 0, stream>>>(Y, WFCl, 384, fc_b + l * 1536,
                                                      G, nullptr, 1536, 384);
        gemm_bt<2><<<dim3(3, 146), 256, 0, stream>>>(G, WFC2Tl, 1536, fc2_b + l * 384,
                                                     XW, XW, 384, 1536);
        // MLP half 1: rows [18688, 37248)
        gemm_bt<1><<<dim3(12, 145), 256, 0, stream>>>(Y + M0 * 384, WFCl, 384, fc_b + l * 1536,
                                                      G, nullptr, 1536, 384);
        gemm_bt<2><<<dim3(3, 145), 256, 0, stream>>>(G, WFC2Tl, 1536, fc2_b + l * 384,
                                                     XW + M0 * 384, XW + M0 * 384, 384, 1536);
    }
    // final LN on readout rows -> d_out [128, 384] f32
    ln_kernel<false><<<32, 256, 0, stream>>>(XW, lnf_w, lnf_b, d_out, TT, 290, 128);
}

// Round 12
// 4124.565 us; speedup vs baseline: 1.4524x; 1.0484x over previous
//
#include <hip/hip_runtime.h>

typedef unsigned short u16;
typedef unsigned int u32;

typedef __bf16 bf16x8 __attribute__((ext_vector_type(8)));
typedef float  f32x4  __attribute__((ext_vector_type(4)));

#define N_EMBD 384
#define TT     291
#define NB     128

__device__ __forceinline__ u16 f2bf(float x) {
    union { float f; u32 u; } v; v.f = x;
    u32 r = v.u + 0x7FFFu + ((v.u >> 16) & 1u);
    return (u16)(r >> 16);
}
__device__ __forceinline__ float bfl(u32 u) { return __uint_as_float(u << 16); }
__device__ __forceinline__ float bfh(u32 u) { return __uint_as_float(u & 0xFFFF0000u); }

// R17: exp2 + hw-rcp form — avoids __expf's extra mul and the PRECISE f32
// division sequence (no fast-math flags). Limits: x->-inf: e=0 -> t=-1 -> 0;
// x->+inf: e=inf -> rcp=0 -> t=1 -> x.  rcp error <=1ulp, negligible here.
__device__ __forceinline__ float gelu_f(float x) {
    float u = 0.7978845608028654f * x * (1.f + 0.044715f * x * x);
    float e = __builtin_amdgcn_exp2f(u * 2.885390081777927f);   // e^{2u}
    float t = 1.f - 2.f * __builtin_amdgcn_rcpf(e + 1.f);       // tanh(u)
    return 0.5f * x * (1.f + t);
}

// async global->LDS DMA, 16B per lane. LDS dest must be wave-uniform base +
// lane*16 in lane order (m104/m108) — caller guarantees the mapping.
__device__ __forceinline__ void load16_lds(const u16* g, u16* l) {
    __builtin_amdgcn_global_load_lds(
        (const __attribute__((address_space(1))) u32*)g,
        (__attribute__((address_space(3))) u32*)l, 16, 0, 0);
}

// ---------------------------------------------------------------------------
// 32x32 transpose+convert tile body: out[c0+rr][r0+cc] = in[r0+cc][c0+rr]
// ---------------------------------------------------------------------------
__device__ __forceinline__ void tr_tile(const float* __restrict__ src,
                                        u16* __restrict__ dst,
                                        int R, int C, int r0, int c0, int tid) {
    __shared__ float tile[32][33];
    int cc = tid & 31, rr0 = tid >> 5;
#pragma unroll
    for (int s = 0; s < 4; ++s) {
        int rr = rr0 + s * 8;
        tile[rr][cc] = src[(size_t)(r0 + rr) * C + c0 + cc];
    }
    __syncthreads();
#pragma unroll
    for (int s = 0; s < 4; ++s) {
        int rr = rr0 + s * 8;
        dst[(size_t)(c0 + rr) * R + (r0 + cc)] = f2bf(tile[cc][rr]);
    }
}

// generic: in[R][C] f32 -> out[C][R] bf16, grid (C/32, R/32)
__global__ __launch_bounds__(256) void transpose_cvt(const float* __restrict__ in,
                                                     u16* __restrict__ out, int R, int C) {
    tr_tile(in, out, R, C, blockIdx.y * 32, blockIdx.x * 32, threadIdx.x);
}

// fused per-layer weight transpose: all 4 matrices of layer l, grid 1728
__global__ __launch_bounds__(256) void transpose_layer(const float* __restrict__ attn_w,
                                                       const float* __restrict__ proj_w,
                                                       const float* __restrict__ fc_w,
                                                       const float* __restrict__ fc2_w,
                                                       u16* __restrict__ wqkv,
                                                       u16* __restrict__ wproj,
                                                       u16* __restrict__ wfc,
                                                       u16* __restrict__ wfc2t,
                                                       int l) {
    int t = blockIdx.x;
    const float* src; u16* dst; int R, C, tx, ty;
    if (t < 432)       { int i = t;        src = attn_w + (size_t)l * 384 * 1152; dst = wqkv;  R = 384;  C = 1152; tx = i % 36; ty = i / 36; }
    else if (t < 576)  { int i = t - 432;  src = proj_w + (size_t)l * 384 * 384;  dst = wproj; R = 384;  C = 384;  tx = i % 12; ty = i / 12; }
    else if (t < 1152) { int i = t - 576;  src = fc_w   + (size_t)l * 384 * 1536; dst = wfc;   R = 384;  C = 1536; tx = i % 48; ty = i / 48; }
    else               { int i = t - 1152; src = fc2_w  + (size_t)l * 1536 * 384; dst = wfc2t; R = 1536; C = 384;  tx = i % 12; ty = i / 12; }
    tr_tile(src, dst, R, C, ty * 32, tx * 32, threadIdx.x);
}

// ---------------------------------------------------------------------------
// bf16 MFMA GEMM:  C[M,N] = A[M,K] @ B[K,N]
// A row-major bf16 (row stride K), BT row-major bf16 [N][ldb] (B^T slice).
// Tile 128x128, BK=64, 256 threads (4 waves = 2x2 of 64x64, each 4x4 MFMA).
// LDS: unpadded [128][64] via global_load_lds, 3-bit XOR col-group swizzle.
// XCD-chunked bijective blockIdx swizzle (T1/m204) for A-panel L2 locality.
//
// R17: 2-PHASE double-buffered staging (T3-minimum, m248v2). Old loop was
// stage -> barrier(full HBM-latency drain) -> compute -> barrier, 6x at
// K=384 — latency never overlapped compute (fc: 79us, all pipes <43%).
// Now: prefetch K-tile t+1 into buf^1 BEFORE computing buf, ONE barrier per
// iter; the barrier's implicit vmcnt(0) lands after ~400cy of MFMA hides
// most of the load latency. Race-safe: prefetch writes the buffer whose
// readers finished at the previous barrier. LDS 64KB -> 2 blocks/CU
// (matches measured effective occupancy anyway).
// K must be a multiple of 64.
// MODE 0: out bf16 = acc+bias        MODE 1: out bf16 = gelu(acc+bias)
// MODE 2: out bf16 = resid(bf16)+acc+bias
// MODE 3: out f32  = acc+bias
// out row stride = N. grid (N/128, ceil(M/128))
// ---------------------------------------------------------------------------
template<int MODE>
__global__ __launch_bounds__(256) void gemm_bt(const u16* __restrict__ A,
                                               const u16* __restrict__ BT, int ldb,
                                               const float* __restrict__ bias,
                                               void* __restrict__ out,
                                               const u16* __restrict__ resid,
                                               int N, int K) {
    __shared__ u16 As[2][128 * 64];   // 2 x 16 KB
    __shared__ u16 Bs[2][128 * 64];   // 2 x 16 KB
    int tid = threadIdx.x;
    int lane = tid & 63, wave = tid >> 6;
    int wr = wave >> 1, wc = wave & 1;

    // ---- XCD-chunked bijective block swizzle (m204) ----
    int nwg  = gridDim.x * gridDim.y;
    int orig = blockIdx.y * gridDim.x + blockIdx.x;
    int qq = nwg >> 3, rr = nwg & 7;
    int xcd = orig & 7, idx0 = orig >> 3;
    int wg = (xcd < rr ? xcd * (qq + 1) : rr * (qq + 1) + (xcd - rr) * qq) + idx0;
    int bx = wg % gridDim.x, by = wg / gridDim.x;

    const u16* Ab = A  + (size_t)by * 128 * K;
    const u16* Bb = BT + (size_t)bx * 128 * ldb;

    f32x4 acc[4][4];
#pragma unroll
    for (int i = 0; i < 4; ++i)
#pragma unroll
        for (int j = 0; j < 4; ++j)
#pragma unroll
            for (int r = 0; r < 4; ++r) acc[i][j][r] = 0.f;

    int r16  = lane & 15;
    int quad = lane >> 4;
    int sw   = r16 & 7;

    // staging map: seg in [0,1024), 16B each; row = seg>>3, LDS slot cg = seg&7
    // holds global col-group (seg&7) ^ (row&7).
    int srow[4], scol[4];
#pragma unroll
    for (int s = 0; s < 4; ++s) {
        int seg = s * 256 + tid;
        srow[s] = seg >> 3;
        scol[s] = (((seg & 7) ^ (srow[s] & 7)) << 3);
    }

    // prologue: stage K-tile 0 into buffer 0
#pragma unroll
    for (int s = 0; s < 4; ++s) {
        int seg = s * 256 + tid;
        load16_lds(Ab + (size_t)srow[s] * K   + scol[s], &As[0][seg * 8]);
        load16_lds(Bb + (size_t)srow[s] * ldb + scol[s], &Bs[0][seg * 8]);
    }
    __syncthreads();

    int nit = K >> 6, cur = 0;
    for (int it = 0; it < nit; ++it) {
        if (it + 1 < nit) {
            int ktn = (it + 1) << 6;
#pragma unroll
            for (int s = 0; s < 4; ++s) {
                int seg = s * 256 + tid;
                load16_lds(Ab + (size_t)srow[s] * K   + ktn + scol[s], &As[cur ^ 1][seg * 8]);
                load16_lds(Bb + (size_t)srow[s] * ldb + ktn + scol[s], &Bs[cur ^ 1][seg * 8]);
            }
        }
#pragma unroll
        for (int kk = 0; kk < 2; ++kk) {     // k-offsets 0, 32 within the 64-slice
            bf16x8 af[4], bff[4];
#pragma unroll
            for (int i = 0; i < 4; ++i) {
                int cg = ((kk * 4 + quad) ^ sw) << 3;
                af[i]  = *(const bf16x8*)&As[cur][(wr * 64 + i * 16 + r16) * 64 + cg];
                bff[i] = *(const bf16x8*)&Bs[cur][(wc * 64 + i * 16 + r16) * 64 + cg];
            }
#pragma unroll
            for (int i = 0; i < 4; ++i)
#pragma unroll
                for (int j = 0; j < 4; ++j)
                    acc[i][j] = __builtin_amdgcn_mfma_f32_16x16x32_bf16(af[i], bff[j], acc[i][j], 0, 0, 0);
        }
        __syncthreads();   // implicit vmcnt(0): prefetch buffer ready for next iter
        cur ^= 1;
    }

    int rbase = (lane >> 4) * 4;
#pragma unroll
    for (int i = 0; i < 4; ++i) {
#pragma unroll
        for (int j = 0; j < 4; ++j) {
            int gr0 = by * 128 + wr * 64 + i * 16 + rbase;
            int gc  = bx * 128 + wc * 64 + j * 16 + (lane & 15);
            float bj = bias ? bias[gc] : 0.f;
#pragma unroll
            for (int r = 0; r < 4; ++r) {
                size_t idx = (size_t)(gr0 + r) * N + gc;
                float v = acc[i][j][r] + bj;
                if (MODE == 0)      ((u16*)out)[idx] = f2bf(v);
                else if (MODE == 1) ((u16*)out)[idx] = f2bf(gelu_f(v));
                else if (MODE == 2) {
                    float rv = bfl((u32)resid[idx]);
                    ((u16*)out)[idx] = f2bf(rv + v);
                }
                else                ((float*)out)[idx] = v;
            }
        }
    }
}

// ---------------------------------------------------------------------------
// LayerNorm (bf16 input): rows of 384 bf16 -> 384 (bf16 or f32).
// block 256 = 4 waves, one row per wave. Vectorized u32 (bf16x2) loads;
// bf16 output packed as u32 pairs (G13 — never scalar bf16 loads).
// input row = row*inRowMul + inRowAdd, output row = row.
// ---------------------------------------------------------------------------
template<bool BF16OUT>
__global__ __launch_bounds__(256) void ln_kernel(const u16* __restrict__ x,
                                                 const float* __restrict__ w,
                                                 const float* __restrict__ b,
                                                 void* __restrict__ yout,
                                                 int inRowMul, int inRowAdd, int nRows) {
    int row = blockIdx.x * 4 + (threadIdx.x >> 6);
    if (row >= nRows) return;
    const u32* xr = (const u32*)(x + ((size_t)row * inRowMul + inRowAdd) * N_EMBD);
    int lane = threadIdx.x & 63;
    float vl[3], vh[3], s = 0.f, s2 = 0.f;
#pragma unroll
    for (int j = 0; j < 3; ++j) {
        u32 u = xr[lane + 64 * j];
        float lo = bfl(u), hi = bfh(u);
        vl[j] = lo; vh[j] = hi;
        s += lo + hi; s2 += lo * lo + hi * hi;
    }
#pragma unroll
    for (int off = 32; off > 0; off >>= 1) {
        s  += __shfl_down(s, off);
        s2 += __shfl_down(s2, off);
    }
    float mean = __shfl(s, 0) * (1.f / 384.f);
    float var  = __shfl(s2, 0) * (1.f / 384.f) - mean * mean;
    float rs = rsqrtf(var + 1e-5f);
#pragma unroll
    for (int j = 0; j < 3; ++j) {
        int c = 2 * (lane + 64 * j);
        float ol = (vl[j] - mean) * rs * w[c]     + b[c];
        float oh = (vh[j] - mean) * rs * w[c + 1] + b[c + 1];
        if (BF16OUT) {
            u32 pk = (u32)f2bf(ol) | ((u32)f2bf(oh) << 16);
            ((u32*)yout)[(size_t)row * 192 + lane + 64 * j] = pk;
        } else {
            ((float*)yout)[(size_t)row * N_EMBD + c]     = ol;
            ((float*)yout)[(size_t)row * N_EMBD + c + 1] = oh;
        }
    }
}

// ---------------------------------------------------------------------------
// MFMA attention, v2 (verified, R15). One block (512 thr, 8 waves) per
// (head, batch). qkv bf16 [B*291, 1152] -> o bf16 [B*291, 384].
// VGPR=88, zero spill, 62.4 us measured (R1/R2/R9).
// ---------------------------------------------------------------------------
__global__ __launch_bounds__(512) void attn_mfma(const u16* __restrict__ qkv,
                                                 u16* __restrict__ o) {
    __shared__ __align__(16) u16 Ks[304 * 64];      // 38,912 B, swizzled
    __shared__ __align__(16) u16 Vt[64 * 328];      // 41,984 B
    __shared__ __align__(16) u16 Ps[8 * 16 * 40];   // 10,240 B (per-wave chunks)
    int h = blockIdx.x, b = blockIdx.y;
    int tid = threadIdx.x;
    int lane = tid & 63, wave = tid >> 6;
    int ln = lane & 15, quad = lane >> 4;
    int sw = ln & 7;
    const u16* base = qkv + (size_t)b * TT * 1152;

    // ---- stage K rows 0..290 (+clamped pad rows 291..303) via DMA ----
    // chunk c: LDS group (c&7) holds global col-group (c&7)^(row&7).
    for (int c = tid; c < 304 * 8; c += 512) {
        int row = c >> 3;
        int g   = (c & 7) ^ (row & 7);
        int srow = row < TT ? row : TT - 1;
        load16_lds(base + (size_t)srow * 1152 + 384 + h * 64 + g * 8, &Ks[c * 8]);
    }
    // ---- stage V transposed: Vt[d][key] ----
    for (int s = tid; s < TT * 8; s += 512) {
        int dg = s / TT, k = s - dg * TT;
        uint4 v = *(const uint4*)(base + (size_t)k * 1152 + 768 + h * 64 + dg * 8);
        const u16* pv = (const u16*)&v;
#pragma unroll
        for (int j = 0; j < 8; ++j) Vt[(dg * 8 + j) * 328 + k] = pv[j];
    }
    // zero pad cols 291..327 of Vt (disjoint from staged cols, no race)
    for (int s = tid; s < 64 * 37; s += 512) {
        int d = s / 37, c2 = s - d * 37;
        Vt[d * 328 + TT + c2] = 0;
    }
    __syncthreads();

    // ---- per-wave Q-tiles (19 tiles over 8 waves) ----
    for (int qt = wave; qt < 19; qt += 8) {
        int q0 = qt * 16;
        int qrow = q0 + ln; if (qrow > TT - 1) qrow = TT - 1;
        const u16* qp = base + (size_t)qrow * 1152 + h * 64;
        bf16x8 qf0 = *(const bf16x8*)(qp + quad * 8);
        bf16x8 qf1 = *(const bf16x8*)(qp + 32 + quad * 8);

        f32x4 sc[19];
#pragma unroll
        for (int kt = 0; kt < 19; ++kt) {
            const u16* kr = &Ks[(kt * 16 + ln) * 64];   // (row&7) == sw
            bf16x8 kb0 = *(const bf16x8*)&kr[(quad ^ sw) << 3];
            bf16x8 kb1 = *(const bf16x8*)&kr[((4 | quad) ^ sw) << 3];
            f32x4 z = {0.f, 0.f, 0.f, 0.f};
            z = __builtin_amdgcn_mfma_f32_16x16x32_bf16(qf0, kb0, z, 0, 0, 0);
            sc[kt] = __builtin_amdgcn_mfma_f32_16x16x32_bf16(qf1, kb1, z, 0, 0, 0);
        }

        // softmax on RAW scores; scale folded into the exp argument.
        const float C = 0.18033688011112042f;   // 0.125 * log2(e)
        float linv[4];
#pragma unroll
        for (int r = 0; r < 4; ++r) {
            float m = -1e30f;
            if (qt == 18) {
                // tile containing the readout row (q==290: attends only itself)
                int q = q0 + quad * 4 + r;
#pragma unroll
                for (int kt = 0; kt < 19; ++kt) {
                    int key = kt * 16 + ln;
                    bool ok = (key < TT) && (q != TT - 1 || key == TT - 1);
                    float s = ok ? sc[kt][r] : -1e30f;
                    sc[kt][r] = s;
                    m = fmaxf(m, s);
                }
            } else {
#pragma unroll
                for (int kt = 0; kt < 18; ++kt) m = fmaxf(m, sc[kt][r]);
                float s = (288 + ln < TT) ? sc[18][r] : -1e30f;  // keys 291..303
                sc[18][r] = s;
                m = fmaxf(m, s);
            }
            m = fmaxf(m, __shfl_xor(m, 1));
            m = fmaxf(m, __shfl_xor(m, 2));
            m = fmaxf(m, __shfl_xor(m, 4));
            m = fmaxf(m, __shfl_xor(m, 8));
            float mc = m * C;
            float l = 0.f;
#pragma unroll
            for (int kt = 0; kt < 19; ++kt) {
                float p = __builtin_amdgcn_exp2f(fmaf(sc[kt][r], C, -mc));
                sc[kt][r] = p;
                l += p;
            }
            l += __shfl_xor(l, 1);
            l += __shfl_xor(l, 2);
            l += __shfl_xor(l, 4);
            l += __shfl_xor(l, 8);
            linv[r] = 1.f / l;
        }

        // ---- PV: write one 32-key P chunk, consume it, repeat (wave-sync) ----
        u16* Pw = &Ps[wave * 16 * 40];
        f32x4 of[4];
#pragma unroll
        for (int nt = 0; nt < 4; ++nt)
#pragma unroll
            for (int r = 0; r < 4; ++r) of[nt][r] = 0.f;
#pragma unroll
        for (int kt2 = 0; kt2 < 10; ++kt2) {
#pragma unroll
            for (int half = 0; half < 2; ++half) {
                int kt = kt2 * 2 + half;
#pragma unroll
                for (int r = 0; r < 4; ++r) {
                    float v = (kt < 19) ? sc[kt][r] : 0.f;   // kt==19: zero pad
                    Pw[(quad * 4 + r) * 40 + half * 16 + ln] = f2bf(v);
                }
            }
            bf16x8 pa = *(const bf16x8*)&Pw[ln * 40 + quad * 8];
#pragma unroll
            for (int nt = 0; nt < 4; ++nt) {
                bf16x8 vb = *(const bf16x8*)&Vt[(nt * 16 + ln) * 328 + kt2 * 32 + quad * 8];
                of[nt] = __builtin_amdgcn_mfma_f32_16x16x32_bf16(pa, vb, of[nt], 0, 0, 0);
            }
        }

#pragma unroll
        for (int nt = 0; nt < 4; ++nt) {
#pragma unroll
            for (int r = 0; r < 4; ++r) {
                int q = q0 + quad * 4 + r;
                if (q < TT)
                    o[((size_t)(b * TT + q)) * N_EMBD + h * 64 + nt * 16 + ln] =
                        f2bf(of[nt][r] * linv[r]);
            }
        }
    }
}

// ---------------------------------------------------------------------------
// Tokenizer helpers (XW is bf16)
// ---------------------------------------------------------------------------
__global__ __launch_bounds__(256) void patchify_kernel(const float* __restrict__ images,
                                                       u16* __restrict__ P) {
    int idx = blockIdx.x * 256 + threadIdx.x;  // 36864*192 exact
    int col = idx % 192, row = idx / 192;
    int p = row % 144, bt = row / 144;
    int c = col % 3, pp = col / 3;
    int pw = pp & 7, ph = pp >> 3;
    int hp = p / 12, wp = p % 12;
    float v = images[(((size_t)bt * 3 + c) * 96 + hp * 8 + ph) * 96 + wp * 8 + pw];
    P[idx] = f2bf(v);
}

__global__ __launch_bounds__(256) void img_scatter_kernel(const float* __restrict__ imgtok,
                                                          const float* __restrict__ temb,
                                                          const float* __restrict__ pos,
                                                          u16* __restrict__ xw) {
    int idx = blockIdx.x * 256 + threadIdx.x;  // 36864*384 exact
    int n = idx % 384, row = idx / 384;
    int p = row % 144, bt = row / 144;
    int t = bt & 1, b = bt >> 1;
    int tok = t * 145 + 1 + p;
    xw[((size_t)b * TT + tok) * N_EMBD + n] =
        f2bf(imgtok[idx] + temb[t * N_EMBD + n] + pos[(size_t)tok * N_EMBD + n]);
}

__global__ __launch_bounds__(384) void st_kernel(const float* __restrict__ state,
                                                 const float* __restrict__ w1,
                                                 const float* __restrict__ b1,
                                                 const float* __restrict__ w2,
                                                 const float* __restrict__ b2,
                                                 const float* __restrict__ temb,
                                                 const float* __restrict__ pos,
                                                 u16* __restrict__ xw) {
    int bt = blockIdx.x;
    int t = bt & 1, b = bt >> 1;
    int n = threadIdx.x;
    float s0 = state[bt * 2], s1 = state[bt * 2 + 1];
    float acc = b2[n];
#pragma unroll
    for (int j = 0; j < 32; ++j) {
        float hh = fmaxf(s0 * w1[j] + s1 * w1[32 + j] + b1[j], 0.f);
        acc += hh * w2[j * N_EMBD + n];
    }
    int tok = t * 145;
    xw[((size_t)b * TT + tok) * N_EMBD + n] =
        f2bf(acc + temb[t * N_EMBD + n] + pos[(size_t)tok * N_EMBD + n]);
}

__global__ __launch_bounds__(256) void ro_kernel(const float* __restrict__ readout,
                                                 const float* __restrict__ pos,
                                                 u16* __restrict__ xw) {
    int idx = blockIdx.x * 256 + threadIdx.x;  // 128*384 exact
    int n = idx % 384, b = idx / 384;
    xw[((size_t)b * TT + 290) * N_EMBD + n] = f2bf(readout[n] + pos[(size_t)290 * N_EMBD + n]);
}

// ---------------------------------------------------------------------------
// Workspace layout (all offsets 256B-aligned; XW region holds bf16
// [37248,384] = 28.6 MB, rest of the old slot unused).
// ---------------------------------------------------------------------------
extern "C" void kernel_launch(void* const* d_in, const int* in_sizes, int n_in,
                              void* d_out, int out_size, void* d_ws, size_t ws_size,
                              hipStream_t stream) {
    const float* images   = (const float*)d_in[0];
    const float* state    = (const float*)d_in[1];
    const float* img_w    = (const float*)d_in[2];
    const float* img_b    = (const float*)d_in[3];
    const float* img_temb = (const float*)d_in[4];
    const float* st_w1    = (const float*)d_in[5];
    const float* st_b1    = (const float*)d_in[6];
    const float* st_w2    = (const float*)d_in[7];
    const float* st_b2    = (const float*)d_in[8];
    const float* st_temb  = (const float*)d_in[9];
    const float* readout  = (const float*)d_in[10];
    const float* pos      = (const float*)d_in[11];
    const float* ln1_w    = (const float*)d_in[12];
    const float* ln1_b    = (const float*)d_in[13];
    const float* attn_w   = (const float*)d_in[14];
    const float* attn_b   = (const float*)d_in[15];
    const float* proj_w   = (const float*)d_in[16];
    const float* proj_b   = (const float*)d_in[17];
    const float* ln2_w    = (const float*)d_in[18];
    const float* ln2_b    = (const float*)d_in[19];
    const float* fc_w     = (const float*)d_in[20];
    const float* fc_b     = (const float*)d_in[21];
    const float* fc2_w    = (const float*)d_in[22];
    const float* fc2_b    = (const float*)d_in[23];
    const float* lnf_w    = (const float*)d_in[24];
    const float* lnf_b    = (const float*)d_in[25];

    char* ws = (char*)d_ws;
    u16*   XW   = (u16*)(ws);                      // bf16 residual stream
    u16*   Y    = (u16*)(ws + 57212928ull);       // also O (attn output)
    u16*   SH   = (u16*)(ws + 85819392ull);       // QKV | G | setup
    u16*   QKV  = SH;
    u16*   G    = SH;
    u16*   P    = SH;                              // setup: patches [36864,192]
    float* IMGT = (float*)(ws + 85819392ull + 14155776ull);  // setup: [36864,384] f32
    u16*   WQKVl  = (u16*)(ws + 171638784ull);    // [1152][384]
    u16*   WPROJl = (u16*)(ws + 172523520ull);    // [384][384]
    u16*   WFCl   = (u16*)(ws + 172818432ull);    // [1536][384]
    u16*   WFC2Tl = (u16*)(ws + 173998080ull);    // [384][1536]
    u16*   WIMG   = (u16*)(ws + 175177728ull);    // [384][192]

    // ---- tokenizers -> XW [128*291, 384] bf16 ----
    transpose_cvt<<<dim3(12, 6), 256, 0, stream>>>(img_w, WIMG, 192, 384);
    patchify_kernel<<<27648, 256, 0, stream>>>(images, P);
    gemm_bt<3><<<dim3(3, 288), 256, 0, stream>>>(P, WIMG, 192, img_b, IMGT, nullptr, 384, 192);
    img_scatter_kernel<<<55296, 256, 0, stream>>>(IMGT, img_temb, pos, XW);
    st_kernel<<<256, 384, 0, stream>>>(state, st_w1, st_b1, st_w2, st_b2, st_temb, pos, XW);
    ro_kernel<<<192, 256, 0, stream>>>(readout, pos, XW);

    // ---- transformer layers (M = 37248 = 128*291) ----
    // Residual stream XW is bf16: residual adds happen in f32 inside the
    // gemm epilogue (acc + bf16-resid), rounded once per junction.
    // MLP is M-split (146 + 145 row-blocks): full-width G half fits the QKV
    // region and fc2 runs as ONE K=1536 GEMM per half.
    const size_t M0 = 18688;   // 146 * 128
    for (int l = 0; l < 12; ++l) {
        transpose_layer<<<1728, 256, 0, stream>>>(attn_w, proj_w, fc_w, fc2_w,
                                                  WQKVl, WPROJl, WFCl, WFC2Tl, l);
        ln_kernel<true><<<9312, 256, 0, stream>>>(XW, ln1_w + l * 384, ln1_b + l * 384, Y, 1, 0, 37248);
        gemm_bt<0><<<dim3(9, 291), 256, 0, stream>>>(Y, WQKVl, 384, attn_b + l * 1152,
                                                     QKV, nullptr, 1152, 384);
        attn_mfma<<<dim3(6, 128), 512, 0, stream>>>(QKV, Y);   // O aliases Y
        gemm_bt<2><<<dim3(3, 291), 256, 0, stream>>>(Y, WPROJl, 384, proj_b + l * 384,
                                                     XW, XW, 384, 384);
        ln_kernel<true><<<9312, 256, 0, stream>>>(XW, ln2_w + l * 384, ln2_b + l * 384, Y, 1, 0, 37248);
        // MLP half 0: rows [0, 18688)
        gemm_bt<1><<<dim3(12, 146), 256, 0, stream>>>(Y, WFCl, 384, fc_b + l * 1536,
                                                      G, nullptr, 1536, 384);
        gemm_bt<2><<<dim3(3, 146), 256, 0, stream>>>(G, WFC2Tl, 1536, fc2_b + l * 384,
                                                     XW, XW, 384, 1536);
        // MLP half 1: rows [18688, 37248)
        gemm_bt<1><<<dim3(12, 145), 256, 0, stream>>>(Y + M0 * 384, WFCl, 384, fc_b + l * 1536,
                                                      G, nullptr, 1536, 384);
        gemm_bt<2><<<dim3(3, 145), 256, 0, stream>>>(G, WFC2Tl, 1536, fc2_b + l * 384,
                                                     XW + M0 * 384, XW + M0 * 384, 384, 1536);
    }
    // final LN on readout rows -> d_out [128, 384] f32
    ln_kernel<false><<<32, 256, 0, stream>>>(XW, lnf_w, lnf_b, d_out, TT, 290, 128);
}

// Round 13
// 4036.596 us; speedup vs baseline: 1.4840x; 1.0218x over previous
//
#include <hip/hip_runtime.h>

typedef unsigned short u16;
typedef unsigned int u32;

typedef __bf16 bf16x8 __attribute__((ext_vector_type(8)));
typedef float  f32x4  __attribute__((ext_vector_type(4)));
typedef short  s16x4  __attribute__((ext_vector_type(4)));
typedef short  s16x8  __attribute__((ext_vector_type(8)));

#define N_EMBD 384
#define TT     291
#define NB     128

__device__ __forceinline__ u16 f2bf(float x) {
    union { float f; u32 u; } v; v.f = x;
    u32 r = v.u + 0x7FFFu + ((v.u >> 16) & 1u);
    return (u16)(r >> 16);
}
__device__ __forceinline__ float bfl(u32 u) { return __uint_as_float(u << 16); }
__device__ __forceinline__ float bfh(u32 u) { return __uint_as_float(u & 0xFFFF0000u); }

// exp2 + hw-rcp form — avoids __expf's extra mul and the PRECISE f32
// division sequence (no fast-math flags). Limits: x->-inf: e=0 -> t=-1 -> 0;
// x->+inf: e=inf -> rcp=0 -> t=1 -> x.  rcp error <=1ulp, negligible here.
__device__ __forceinline__ float gelu_f(float x) {
    float u = 0.7978845608028654f * x * (1.f + 0.044715f * x * x);
    float e = __builtin_amdgcn_exp2f(u * 2.885390081777927f);   // e^{2u}
    float t = 1.f - 2.f * __builtin_amdgcn_rcpf(e + 1.f);       // tanh(u)
    return 0.5f * x * (1.f + t);
}

// async global->LDS DMA, 16B per lane. LDS dest must be wave-uniform base +
// lane*16 in lane order (m104/m108) — caller guarantees the mapping.
__device__ __forceinline__ void load16_lds(const u16* g, u16* l) {
    __builtin_amdgcn_global_load_lds(
        (const __attribute__((address_space(1))) u32*)g,
        (__attribute__((address_space(3))) u32*)l, 16, 0, 0);
}

// ---------------------------------------------------------------------------
// 32x32 transpose+convert tile body: out[c0+rr][r0+cc] = in[r0+cc][c0+rr]
// ---------------------------------------------------------------------------
__device__ __forceinline__ void tr_tile(const float* __restrict__ src,
                                        u16* __restrict__ dst,
                                        int R, int C, int r0, int c0, int tid) {
    __shared__ float tile[32][33];
    int cc = tid & 31, rr0 = tid >> 5;
#pragma unroll
    for (int s = 0; s < 4; ++s) {
        int rr = rr0 + s * 8;
        tile[rr][cc] = src[(size_t)(r0 + rr) * C + c0 + cc];
    }
    __syncthreads();
#pragma unroll
    for (int s = 0; s < 4; ++s) {
        int rr = rr0 + s * 8;
        dst[(size_t)(c0 + rr) * R + (r0 + cc)] = f2bf(tile[cc][rr]);
    }
}

// generic: in[R][C] f32 -> out[C][R] bf16, grid (C/32, R/32)
__global__ __launch_bounds__(256) void transpose_cvt(const float* __restrict__ in,
                                                     u16* __restrict__ out, int R, int C) {
    tr_tile(in, out, R, C, blockIdx.y * 32, blockIdx.x * 32, threadIdx.x);
}

// fused per-layer weight transpose: all 4 matrices of layer l, grid 1728
__global__ __launch_bounds__(256) void transpose_layer(const float* __restrict__ attn_w,
                                                       const float* __restrict__ proj_w,
                                                       const float* __restrict__ fc_w,
                                                       const float* __restrict__ fc2_w,
                                                       u16* __restrict__ wqkv,
                                                       u16* __restrict__ wproj,
                                                       u16* __restrict__ wfc,
                                                       u16* __restrict__ wfc2t,
                                                       int l) {
    int t = blockIdx.x;
    const float* src; u16* dst; int R, C, tx, ty;
    if (t < 432)       { int i = t;        src = attn_w + (size_t)l * 384 * 1152; dst = wqkv;  R = 384;  C = 1152; tx = i % 36; ty = i / 36; }
    else if (t < 576)  { int i = t - 432;  src = proj_w + (size_t)l * 384 * 384;  dst = wproj; R = 384;  C = 384;  tx = i % 12; ty = i / 12; }
    else if (t < 1152) { int i = t - 576;  src = fc_w   + (size_t)l * 384 * 1536; dst = wfc;   R = 384;  C = 1536; tx = i % 48; ty = i / 48; }
    else               { int i = t - 1152; src = fc2_w  + (size_t)l * 1536 * 384; dst = wfc2t; R = 1536; C = 384;  tx = i % 12; ty = i / 12; }
    tr_tile(src, dst, R, C, ty * 32, tx * 32, threadIdx.x);
}

// ---------------------------------------------------------------------------
// bf16 MFMA GEMM:  C[M,N] = A[M,K] @ B[K,N]
// A row-major bf16 (row stride K), BT row-major bf16 [N][ldb] (B^T slice).
// Tile 128x128, BK=64, 256 threads (4 waves = 2x2 of 64x64, each 4x4 MFMA).
// LDS: unpadded [128][64] via global_load_lds, 3-bit XOR col-group swizzle.
// XCD-chunked bijective blockIdx swizzle (T1/m204) for A-panel L2 locality.
// 2-PHASE double-buffered staging (R17, verified R12: fc 79 -> <62 us).
// K must be a multiple of 64.
// MODE 0: out bf16 = acc+bias        MODE 1: out bf16 = gelu(acc+bias)
// MODE 2: out bf16 = resid(bf16)+acc+bias
// MODE 3: out f32  = acc+bias
// out row stride = N. grid (N/128, ceil(M/128))
// ---------------------------------------------------------------------------
template<int MODE>
__global__ __launch_bounds__(256) void gemm_bt(const u16* __restrict__ A,
                                               const u16* __restrict__ BT, int ldb,
                                               const float* __restrict__ bias,
                                               void* __restrict__ out,
                                               const u16* __restrict__ resid,
                                               int N, int K) {
    __shared__ u16 As[2][128 * 64];   // 2 x 16 KB
    __shared__ u16 Bs[2][128 * 64];   // 2 x 16 KB
    int tid = threadIdx.x;
    int lane = tid & 63, wave = tid >> 6;
    int wr = wave >> 1, wc = wave & 1;

    // ---- XCD-chunked bijective block swizzle (m204) ----
    int nwg  = gridDim.x * gridDim.y;
    int orig = blockIdx.y * gridDim.x + blockIdx.x;
    int qq = nwg >> 3, rr = nwg & 7;
    int xcd = orig & 7, idx0 = orig >> 3;
    int wg = (xcd < rr ? xcd * (qq + 1) : rr * (qq + 1) + (xcd - rr) * qq) + idx0;
    int bx = wg % gridDim.x, by = wg / gridDim.x;

    const u16* Ab = A  + (size_t)by * 128 * K;
    const u16* Bb = BT + (size_t)bx * 128 * ldb;

    f32x4 acc[4][4];
#pragma unroll
    for (int i = 0; i < 4; ++i)
#pragma unroll
        for (int j = 0; j < 4; ++j)
#pragma unroll
            for (int r = 0; r < 4; ++r) acc[i][j][r] = 0.f;

    int r16  = lane & 15;
    int quad = lane >> 4;
    int sw   = r16 & 7;

    // staging map: seg in [0,1024), 16B each; row = seg>>3, LDS slot cg = seg&7
    // holds global col-group (seg&7) ^ (row&7).
    int srow[4], scol[4];
#pragma unroll
    for (int s = 0; s < 4; ++s) {
        int seg = s * 256 + tid;
        srow[s] = seg >> 3;
        scol[s] = (((seg & 7) ^ (srow[s] & 7)) << 3);
    }

    // prologue: stage K-tile 0 into buffer 0
#pragma unroll
    for (int s = 0; s < 4; ++s) {
        int seg = s * 256 + tid;
        load16_lds(Ab + (size_t)srow[s] * K   + scol[s], &As[0][seg * 8]);
        load16_lds(Bb + (size_t)srow[s] * ldb + scol[s], &Bs[0][seg * 8]);
    }
    __syncthreads();

    int nit = K >> 6, cur = 0;
    for (int it = 0; it < nit; ++it) {
        if (it + 1 < nit) {
            int ktn = (it + 1) << 6;
#pragma unroll
            for (int s = 0; s < 4; ++s) {
                int seg = s * 256 + tid;
                load16_lds(Ab + (size_t)srow[s] * K   + ktn + scol[s], &As[cur ^ 1][seg * 8]);
                load16_lds(Bb + (size_t)srow[s] * ldb + ktn + scol[s], &Bs[cur ^ 1][seg * 8]);
            }
        }
#pragma unroll
        for (int kk = 0; kk < 2; ++kk) {     // k-offsets 0, 32 within the 64-slice
            bf16x8 af[4], bff[4];
#pragma unroll
            for (int i = 0; i < 4; ++i) {
                int cg = ((kk * 4 + quad) ^ sw) << 3;
                af[i]  = *(const bf16x8*)&As[cur][(wr * 64 + i * 16 + r16) * 64 + cg];
                bff[i] = *(const bf16x8*)&Bs[cur][(wc * 64 + i * 16 + r16) * 64 + cg];
            }
#pragma unroll
            for (int i = 0; i < 4; ++i)
#pragma unroll
                for (int j = 0; j < 4; ++j)
                    acc[i][j] = __builtin_amdgcn_mfma_f32_16x16x32_bf16(af[i], bff[j], acc[i][j], 0, 0, 0);
        }
        __syncthreads();   // implicit vmcnt(0): prefetch buffer ready for next iter
        cur ^= 1;
    }

    int rbase = (lane >> 4) * 4;
#pragma unroll
    for (int i = 0; i < 4; ++i) {
#pragma unroll
        for (int j = 0; j < 4; ++j) {
            int gr0 = by * 128 + wr * 64 + i * 16 + rbase;
            int gc  = bx * 128 + wc * 64 + j * 16 + (lane & 15);
            float bj = bias ? bias[gc] : 0.f;
#pragma unroll
            for (int r = 0; r < 4; ++r) {
                size_t idx = (size_t)(gr0 + r) * N + gc;
                float v = acc[i][j][r] + bj;
                if (MODE == 0)      ((u16*)out)[idx] = f2bf(v);
                else if (MODE == 1) ((u16*)out)[idx] = f2bf(gelu_f(v));
                else if (MODE == 2) {
                    float rv = bfl((u32)resid[idx]);
                    ((u16*)out)[idx] = f2bf(rv + v);
                }
                else                ((float*)out)[idx] = v;
            }
        }
    }
}

// ---------------------------------------------------------------------------
// LayerNorm (bf16 input): rows of 384 bf16 -> 384 (bf16 or f32).
// block 256 = 4 waves, one row per wave. Vectorized u32 (bf16x2) loads;
// bf16 output packed as u32 pairs (G13 — never scalar bf16 loads).
// input row = row*inRowMul + inRowAdd, output row = row.
// ---------------------------------------------------------------------------
template<bool BF16OUT>
__global__ __launch_bounds__(256) void ln_kernel(const u16* __restrict__ x,
                                                 const float* __restrict__ w,
                                                 const float* __restrict__ b,
                                                 void* __restrict__ yout,
                                                 int inRowMul, int inRowAdd, int nRows) {
    int row = blockIdx.x * 4 + (threadIdx.x >> 6);
    if (row >= nRows) return;
    const u32* xr = (const u32*)(x + ((size_t)row * inRowMul + inRowAdd) * N_EMBD);
    int lane = threadIdx.x & 63;
    float vl[3], vh[3], s = 0.f, s2 = 0.f;
#pragma unroll
    for (int j = 0; j < 3; ++j) {
        u32 u = xr[lane + 64 * j];
        float lo = bfl(u), hi = bfh(u);
        vl[j] = lo; vh[j] = hi;
        s += lo + hi; s2 += lo * lo + hi * hi;
    }
#pragma unroll
    for (int off = 32; off > 0; off >>= 1) {
        s  += __shfl_down(s, off);
        s2 += __shfl_down(s2, off);
    }
    float mean = __shfl(s, 0) * (1.f / 384.f);
    float var  = __shfl(s2, 0) * (1.f / 384.f) - mean * mean;
    float rs = rsqrtf(var + 1e-5f);
#pragma unroll
    for (int j = 0; j < 3; ++j) {
        int c = 2 * (lane + 64 * j);
        float ol = (vl[j] - mean) * rs * w[c]     + b[c];
        float oh = (vh[j] - mean) * rs * w[c + 1] + b[c + 1];
        if (BF16OUT) {
            u32 pk = (u32)f2bf(ol) | ((u32)f2bf(oh) << 16);
            ((u32*)yout)[(size_t)row * 192 + lane + 64 * j] = pk;
        } else {
            ((float*)yout)[(size_t)row * N_EMBD + c]     = ol;
            ((float*)yout)[(size_t)row * N_EMBD + c + 1] = oh;
        }
    }
}

// ---------------------------------------------------------------------------
// MFMA attention, v2.1 (R19). One block (512 thr, 8 waves) per (head, batch).
// qkv bf16 [B*291, 1152] -> o bf16 [B*291, 384].
//
// R18 evidence: 2.97M bank-conflict cycles from Ps writes — stride 40 u16
// (dw-stride 20): quads 0/2 and 1/3 alias (4-way). Fix: stride 44 (dw 22,
// gcd(22,32)=2): per write the 4 quads start at +{0,24,16,8} each spanning
// 8 dw -> perfectly tiles all 32 banks (2-way b16 pairs = free). Reads drop
// to 2x 8B s16x4 (ln*88B is only 8B-aligned) assembled into the bf16x8 frag.
// T5 setprio(1) wraps the QK and PV MFMA clusters — waves here run
// independent qt phases (m191's +4-7% regime; NOT applied to lockstep gemm).
// VGPR=88-class, zero spill. LDS 92,160 B -> 1 block/CU (unchanged).
// ---------------------------------------------------------------------------
__global__ __launch_bounds__(512) void attn_mfma(const u16* __restrict__ qkv,
                                                 u16* __restrict__ o) {
    __shared__ __align__(16) u16 Ks[304 * 64];      // 38,912 B, swizzled
    __shared__ __align__(16) u16 Vt[64 * 328];      // 41,984 B
    __shared__ __align__(16) u16 Ps[8 * 16 * 44];   // 11,264 B (per-wave chunks)
    int h = blockIdx.x, b = blockIdx.y;
    int tid = threadIdx.x;
    int lane = tid & 63, wave = tid >> 6;
    int ln = lane & 15, quad = lane >> 4;
    int sw = ln & 7;
    const u16* base = qkv + (size_t)b * TT * 1152;

    // ---- stage K rows 0..290 (+clamped pad rows 291..303) via DMA ----
    // chunk c: LDS group (c&7) holds global col-group (c&7)^(row&7).
    for (int c = tid; c < 304 * 8; c += 512) {
        int row = c >> 3;
        int g   = (c & 7) ^ (row & 7);
        int srow = row < TT ? row : TT - 1;
        load16_lds(base + (size_t)srow * 1152 + 384 + h * 64 + g * 8, &Ks[c * 8]);
    }
    // ---- stage V transposed: Vt[d][key] ----
    for (int s = tid; s < TT * 8; s += 512) {
        int dg = s / TT, k = s - dg * TT;
        uint4 v = *(const uint4*)(base + (size_t)k * 1152 + 768 + h * 64 + dg * 8);
        const u16* pv = (const u16*)&v;
#pragma unroll
        for (int j = 0; j < 8; ++j) Vt[(dg * 8 + j) * 328 + k] = pv[j];
    }
    // zero pad cols 291..327 of Vt (disjoint from staged cols, no race)
    for (int s = tid; s < 64 * 37; s += 512) {
        int d = s / 37, c2 = s - d * 37;
        Vt[d * 328 + TT + c2] = 0;
    }
    __syncthreads();

    // ---- per-wave Q-tiles (19 tiles over 8 waves) ----
    for (int qt = wave; qt < 19; qt += 8) {
        int q0 = qt * 16;
        int qrow = q0 + ln; if (qrow > TT - 1) qrow = TT - 1;
        const u16* qp = base + (size_t)qrow * 1152 + h * 64;
        bf16x8 qf0 = *(const bf16x8*)(qp + quad * 8);
        bf16x8 qf1 = *(const bf16x8*)(qp + 32 + quad * 8);

        f32x4 sc[19];
        __builtin_amdgcn_s_setprio(1);
#pragma unroll
        for (int kt = 0; kt < 19; ++kt) {
            const u16* kr = &Ks[(kt * 16 + ln) * 64];   // (row&7) == sw
            bf16x8 kb0 = *(const bf16x8*)&kr[(quad ^ sw) << 3];
            bf16x8 kb1 = *(const bf16x8*)&kr[((4 | quad) ^ sw) << 3];
            f32x4 z = {0.f, 0.f, 0.f, 0.f};
            z = __builtin_amdgcn_mfma_f32_16x16x32_bf16(qf0, kb0, z, 0, 0, 0);
            sc[kt] = __builtin_amdgcn_mfma_f32_16x16x32_bf16(qf1, kb1, z, 0, 0, 0);
        }
        __builtin_amdgcn_s_setprio(0);

        // softmax on RAW scores; scale folded into the exp argument.
        const float C = 0.18033688011112042f;   // 0.125 * log2(e)
        float linv[4];
#pragma unroll
        for (int r = 0; r < 4; ++r) {
            float m = -1e30f;
            if (qt == 18) {
                // tile containing the readout row (q==290: attends only itself)
                int q = q0 + quad * 4 + r;
#pragma unroll
                for (int kt = 0; kt < 19; ++kt) {
                    int key = kt * 16 + ln;
                    bool ok = (key < TT) && (q != TT - 1 || key == TT - 1);
                    float s = ok ? sc[kt][r] : -1e30f;
                    sc[kt][r] = s;
                    m = fmaxf(m, s);
                }
            } else {
#pragma unroll
                for (int kt = 0; kt < 18; ++kt) m = fmaxf(m, sc[kt][r]);
                float s = (288 + ln < TT) ? sc[18][r] : -1e30f;  // keys 291..303
                sc[18][r] = s;
                m = fmaxf(m, s);
            }
            m = fmaxf(m, __shfl_xor(m, 1));
            m = fmaxf(m, __shfl_xor(m, 2));
            m = fmaxf(m, __shfl_xor(m, 4));
            m = fmaxf(m, __shfl_xor(m, 8));
            float mc = m * C;
            float l = 0.f;
#pragma unroll
            for (int kt = 0; kt < 19; ++kt) {
                float p = __builtin_amdgcn_exp2f(fmaf(sc[kt][r], C, -mc));
                sc[kt][r] = p;
                l += p;
            }
            l += __shfl_xor(l, 1);
            l += __shfl_xor(l, 2);
            l += __shfl_xor(l, 4);
            l += __shfl_xor(l, 8);
            linv[r] = 1.f / l;
        }

        // ---- PV: write one 32-key P chunk, consume it, repeat (wave-sync) ----
        u16* Pw = &Ps[wave * 16 * 44];
        f32x4 of[4];
#pragma unroll
        for (int nt = 0; nt < 4; ++nt)
#pragma unroll
            for (int r = 0; r < 4; ++r) of[nt][r] = 0.f;
        __builtin_amdgcn_s_setprio(1);
#pragma unroll
        for (int kt2 = 0; kt2 < 10; ++kt2) {
#pragma unroll
            for (int half = 0; half < 2; ++half) {
                int kt = kt2 * 2 + half;
#pragma unroll
                for (int r = 0; r < 4; ++r) {
                    float v = (kt < 19) ? sc[kt][r] : 0.f;   // kt==19: zero pad
                    Pw[(quad * 4 + r) * 44 + half * 16 + ln] = f2bf(v);
                }
            }
            // two 8B reads (ln*88B is 8B-aligned, not 16B) -> assemble frag
            s16x4 pl = *(const s16x4*)&Pw[ln * 44 + quad * 8];
            s16x4 ph = *(const s16x4*)&Pw[ln * 44 + quad * 8 + 4];
            s16x8 pc = __builtin_shufflevector(pl, ph, 0, 1, 2, 3, 4, 5, 6, 7);
            bf16x8 pa = __builtin_bit_cast(bf16x8, pc);
#pragma unroll
            for (int nt = 0; nt < 4; ++nt) {
                bf16x8 vb = *(const bf16x8*)&Vt[(nt * 16 + ln) * 328 + kt2 * 32 + quad * 8];
                of[nt] = __builtin_amdgcn_mfma_f32_16x16x32_bf16(pa, vb, of[nt], 0, 0, 0);
            }
        }
        __builtin_amdgcn_s_setprio(0);

#pragma unroll
        for (int nt = 0; nt < 4; ++nt) {
#pragma unroll
            for (int r = 0; r < 4; ++r) {
                int q = q0 + quad * 4 + r;
                if (q < TT)
                    o[((size_t)(b * TT + q)) * N_EMBD + h * 64 + nt * 16 + ln] =
                        f2bf(of[nt][r] * linv[r]);
            }
        }
    }
}

// ---------------------------------------------------------------------------
// Tokenizer helpers (XW is bf16)
// ---------------------------------------------------------------------------
__global__ __launch_bounds__(256) void patchify_kernel(const float* __restrict__ images,
                                                       u16* __restrict__ P) {
    int idx = blockIdx.x * 256 + threadIdx.x;  // 36864*192 exact
    int col = idx % 192, row = idx / 192;
    int p = row % 144, bt = row / 144;
    int c = col % 3, pp = col / 3;
    int pw = pp & 7, ph = pp >> 3;
    int hp = p / 12, wp = p % 12;
    float v = images[(((size_t)bt * 3 + c) * 96 + hp * 8 + ph) * 96 + wp * 8 + pw];
    P[idx] = f2bf(v);
}

__global__ __launch_bounds__(256) void img_scatter_kernel(const float* __restrict__ imgtok,
                                                          const float* __restrict__ temb,
                                                          const float* __restrict__ pos,
                                                          u16* __restrict__ xw) {
    int idx = blockIdx.x * 256 + threadIdx.x;  // 36864*384 exact
    int n = idx % 384, row = idx / 384;
    int p = row % 144, bt = row / 144;
    int t = bt & 1, b = bt >> 1;
    int tok = t * 145 + 1 + p;
    xw[((size_t)b * TT + tok) * N_EMBD + n] =
        f2bf(imgtok[idx] + temb[t * N_EMBD + n] + pos[(size_t)tok * N_EMBD + n]);
}

__global__ __launch_bounds__(384) void st_kernel(const float* __restrict__ state,
                                                 const float* __restrict__ w1,
                                                 const float* __restrict__ b1,
                                                 const float* __restrict__ w2,
                                                 const float* __restrict__ b2,
                                                 const float* __restrict__ temb,
                                                 const float* __restrict__ pos,
                                                 u16* __restrict__ xw) {
    int bt = blockIdx.x;
    int t = bt & 1, b = bt >> 1;
    int n = threadIdx.x;
    float s0 = state[bt * 2], s1 = state[bt * 2 + 1];
    float acc = b2[n];
#pragma unroll
    for (int j = 0; j < 32; ++j) {
        float hh = fmaxf(s0 * w1[j] + s1 * w1[32 + j] + b1[j], 0.f);
        acc += hh * w2[j * N_EMBD + n];
    }
    int tok = t * 145;
    xw[((size_t)b * TT + tok) * N_EMBD + n] =
        f2bf(acc + temb[t * N_EMBD + n] + pos[(size_t)tok * N_EMBD + n]);
}

__global__ __launch_bounds__(256) void ro_kernel(const float* __restrict__ readout,
                                                 const float* __restrict__ pos,
                                                 u16* __restrict__ xw) {
    int idx = blockIdx.x * 256 + threadIdx.x;  // 128*384 exact
    int n = idx % 384, b = idx / 384;
    xw[((size_t)b * TT + 290) * N_EMBD + n] = f2bf(readout[n] + pos[(size_t)290 * N_EMBD + n]);
}

// ---------------------------------------------------------------------------
// Workspace layout v2 (R19, all offsets 256B-aligned, max end 175,214,592
// <= 175,325,184):
//   XW  bf16 [37248,384]            @ 0           (28,612,608)
//   Y   bf16 [37248,384]            @ 28,612,608  (28,612,608)
//   G   bf16 [37248,1536]           @ 57,225,216  (114,450,432) — aliases QKV
//     QKV bf16 [37248,1152]         @ 57,225,216  (85,837,824, dead before fc)
//     setup: P [36864,192] bf16     @ 57,225,216  (14,155,776)
//            IMGT [36864,384] f32   @ 71,380,992  (56,623,104)
//            WIMG [384,192] bf16    @ 128,004,096 (147,456)
//   WQKVl  [1152][384]              @ 171,675,648
//   WPROJl [384][384]               @ 172,560,384
//   WFCl   [1536][384]              @ 172,855,296
//   WFC2Tl [384][1536]              @ 174,034,944 (ends 175,214,592)
// Full-M G means fc and fc2 run ONCE per layer (grid (12,291)/(3,291)).
// ---------------------------------------------------------------------------
extern "C" void kernel_launch(void* const* d_in, const int* in_sizes, int n_in,
                              void* d_out, int out_size, void* d_ws, size_t ws_size,
                              hipStream_t stream) {
    const float* images   = (const float*)d_in[0];
    const float* state    = (const float*)d_in[1];
    const float* img_w    = (const float*)d_in[2];
    const float* img_b    = (const float*)d_in[3];
    const float* img_temb = (const float*)d_in[4];
    const float* st_w1    = (const float*)d_in[5];
    const float* st_b1    = (const float*)d_in[6];
    const float* st_w2    = (const float*)d_in[7];
    const float* st_b2    = (const float*)d_in[8];
    const float* st_temb  = (const float*)d_in[9];
    const float* readout  = (const float*)d_in[10];
    const float* pos      = (const float*)d_in[11];
    const float* ln1_w    = (const float*)d_in[12];
    const float* ln1_b    = (const float*)d_in[13];
    const float* attn_w   = (const float*)d_in[14];
    const float* attn_b   = (const float*)d_in[15];
    const float* proj_w   = (const float*)d_in[16];
    const float* proj_b   = (const float*)d_in[17];
    const float* ln2_w    = (const float*)d_in[18];
    const float* ln2_b    = (const float*)d_in[19];
    const float* fc_w     = (const float*)d_in[20];
    const float* fc_b     = (const float*)d_in[21];
    const float* fc2_w    = (const float*)d_in[22];
    const float* fc2_b    = (const float*)d_in[23];
    const float* lnf_w    = (const float*)d_in[24];
    const float* lnf_b    = (const float*)d_in[25];

    char* ws = (char*)d_ws;
    u16*   XW   = (u16*)(ws);                      // bf16 residual stream
    u16*   Y    = (u16*)(ws + 28612608ull);
    u16*   G    = (u16*)(ws + 57225216ull);        // full [37248,1536]
    u16*   QKV  = G;                                // alias (disjoint lifetime)
    u16*   P    = G;                                // setup patches
    float* IMGT = (float*)(ws + 71380992ull);      // setup [36864,384] f32
    u16*   WIMG = (u16*)(ws + 128004096ull);       // setup [384][192]
    u16*   WQKVl  = (u16*)(ws + 171675648ull);     // [1152][384]
    u16*   WPROJl = (u16*)(ws + 172560384ull);     // [384][384]
    u16*   WFCl   = (u16*)(ws + 172855296ull);     // [1536][384]
    u16*   WFC2Tl = (u16*)(ws + 174034944ull);     // [384][1536]

    // ---- tokenizers -> XW [128*291, 384] bf16 ----
    transpose_cvt<<<dim3(12, 6), 256, 0, stream>>>(img_w, WIMG, 192, 384);
    patchify_kernel<<<27648, 256, 0, stream>>>(images, P);
    gemm_bt<3><<<dim3(3, 288), 256, 0, stream>>>(P, WIMG, 192, img_b, IMGT, nullptr, 384, 192);
    img_scatter_kernel<<<55296, 256, 0, stream>>>(IMGT, img_temb, pos, XW);
    st_kernel<<<256, 384, 0, stream>>>(state, st_w1, st_b1, st_w2, st_b2, st_temb, pos, XW);
    ro_kernel<<<192, 256, 0, stream>>>(readout, pos, XW);

    // ---- transformer layers (M = 37248 = 128*291) ----
    for (int l = 0; l < 12; ++l) {
        transpose_layer<<<1728, 256, 0, stream>>>(attn_w, proj_w, fc_w, fc2_w,
                                                  WQKVl, WPROJl, WFCl, WFC2Tl, l);
        ln_kernel<true><<<9312, 256, 0, stream>>>(XW, ln1_w + l * 384, ln1_b + l * 384, Y, 1, 0, 37248);
        gemm_bt<0><<<dim3(9, 291), 256, 0, stream>>>(Y, WQKVl, 384, attn_b + l * 1152,
                                                     QKV, nullptr, 1152, 384);
        attn_mfma<<<dim3(6, 128), 512, 0, stream>>>(QKV, Y);   // O aliases Y
        gemm_bt<2><<<dim3(3, 291), 256, 0, stream>>>(Y, WPROJl, 384, proj_b + l * 384,
                                                     XW, XW, 384, 384);
        ln_kernel<true><<<9312, 256, 0, stream>>>(XW, ln2_w + l * 384, ln2_b + l * 384, Y, 1, 0, 37248);
        // MLP, full M in one dispatch each (G holds [37248,1536])
        gemm_bt<1><<<dim3(12, 291), 256, 0, stream>>>(Y, WFCl, 384, fc_b + l * 1536,
                                                      G, nullptr, 1536, 384);
        gemm_bt<2><<<dim3(3, 291), 256, 0, stream>>>(G, WFC2Tl, 1536, fc2_b + l * 384,
                                                     XW, XW, 384, 1536);
    }
    // final LN on readout rows -> d_out [128, 384] f32
    ln_kernel<false><<<32, 256, 0, stream>>>(XW, lnf_w, lnf_b, d_out, TT, 290, 128);
}